// Round 8
// baseline (251.396 us; speedup 1.0000x reference)
//
#include <hip/hip_runtime.h>

// Problem constants: B=2, obj=4, C=256, H=W=48, N=8, HW=2304
#define HH 48
#define WW 48
#define HWP 2304
#define CC 256
#define NB 8
#define QKROW 2305   // 2304 rows + 1 zero pad row (index 2304) for OOB taps

typedef __attribute__((ext_vector_type(8))) short short8;   // 8 x bf16 = 4 VGPR
typedef __attribute__((ext_vector_type(4))) short bf16x4;   // 4 x bf16 = 8B
typedef __attribute__((ext_vector_type(4))) float floatx4;  // MFMA C/D frag

static __device__ __forceinline__ unsigned short f2bf(float f) {
    union { float f; unsigned u; } v; v.f = f;
    unsigned r = v.u + 0x7fffu + ((v.u >> 16) & 1u);        // RNE
    return (unsigned short)(r >> 16);
}
static __device__ __forceinline__ float bf2f(short v) {
    union { unsigned u; float f; } x; x.u = ((unsigned)(unsigned short)v) << 16;
    return x.f;
}

// ---- tiled transpose q/k -> qkT[b][px][c2] bf16 (64x64 tiles via LDS) ------
__global__ __launch_bounds__(256) void k_tr_qk(const float* __restrict__ q,
        const float* __restrict__ kk, unsigned short* __restrict__ qkT) {
    __shared__ float T[64][65];
    const int pg = blockIdx.x, cg = blockIdx.y;
    const int b = blockIdx.z >> 1, src = blockIdx.z & 1;
    const float* s = (src ? kk : q) + (size_t)b * CC * HWP;
    const int tx = threadIdx.x & 63, ty = threadIdx.x >> 6;
#pragma unroll
    for (int i = 0; i < 16; i++) {
        int cl = ty * 16 + i;
        T[cl][tx] = s[(size_t)(cg * 64 + cl) * HWP + pg * 64 + tx];
    }
    __syncthreads();
#pragma unroll
    for (int i = 0; i < 16; i++) {
        int pxl = ty * 16 + i;
        qkT[((size_t)b * QKROW + pg * 64 + pxl) * 512 + src * 256 + cg * 64 + tx]
            = f2bf(T[tx][pxl]);
    }
}

// ---- tiled transpose value -> vT[n][px][c] bf16 ----------------------------
__global__ __launch_bounds__(256) void k_tr_v(const float* __restrict__ v,
                                              unsigned short* __restrict__ vT) {
    __shared__ float T[64][65];
    const int pg = blockIdx.x, cg = blockIdx.y, n = blockIdx.z;
    const float* s = v + (size_t)n * CC * HWP;
    const int tx = threadIdx.x & 63, ty = threadIdx.x >> 6;
#pragma unroll
    for (int i = 0; i < 16; i++) {
        int cl = ty * 16 + i;
        T[cl][tx] = s[(size_t)(cg * 64 + cl) * HWP + pg * 64 + tx];
    }
    __syncthreads();
#pragma unroll
    for (int i = 0; i < 16; i++) {
        int pxl = ty * 16 + i;
        vT[((size_t)n * HWP + pg * 64 + pxl) * 256 + cg * 64 + tx] = f2bf(T[tx][pxl]);
    }
}

// ---- weight preshuffle into MFMA-fragment order (1KB contiguous frags) -----
// A-operand lane map (16x16x32): lane l holds A[m = l&15][k = (l>>4)*8 + j].
// w1r:  [tap(9)][kk(16)][mtg(16)][l(64)][j(8)]
// wdr:  [tap(9)][kk(8)] [mtg(16)][l(64)][j(8)]
// w2r:  [tap(9)][kk(8)] [mt(2)]  [l(64)][j(8)]   (rows o>=18 zero)
// Last block (7200) zeroes the qkT and featb pad rows (was k_pads).
__global__ __launch_bounds__(256) void k_prep_w(const float* __restrict__ w1,
        const float* __restrict__ dw, const float* __restrict__ w2,
        unsigned short* __restrict__ w1r, unsigned short* __restrict__ wdr,
        unsigned short* __restrict__ w2r, unsigned short* __restrict__ qkT,
        unsigned short* __restrict__ featb) {
    if (blockIdx.x == 7200) {
        int t = threadIdx.x;
#pragma unroll
        for (int b = 0; b < 2; b++) {
            qkT[((size_t)b * QKROW + HWP) * 512 + t] = 0;
            qkT[((size_t)b * QKROW + HWP) * 512 + 256 + t] = 0;
            featb[((size_t)b * QKROW + HWP) * 256 + t] = 0;
        }
        return;
    }
    int idx = blockIdx.x * 256 + threadIdx.x;
    if (idx < 1179648) {
        int j = idx & 7, l = (idx >> 3) & 63, mtg = (idx >> 9) & 15;
        int kk = (idx >> 13) & 15, tap = idx >> 17;
        int o = mtg * 16 + (l & 15);
        int c2 = kk * 32 + (l >> 4) * 8 + j;
        w1r[idx] = f2bf(w1[((size_t)o * 512 + c2) * 9 + tap]);
    } else if (idx < 1179648 + 589824) {
        int i2 = idx - 1179648;
        int j = i2 & 7, l = (i2 >> 3) & 63, mtg = (i2 >> 9) & 15;
        int kk = (i2 >> 13) & 7, tap = i2 >> 16;
        int o = mtg * 16 + (l & 15);
        int c = kk * 32 + (l >> 4) * 8 + j;
        wdr[i2] = f2bf(dw[((size_t)o * 256 + c) * 9 + tap]);
    } else {
        int i2 = idx - 1179648 - 589824;
        int j = i2 & 7, l = (i2 >> 3) & 63, mt = (i2 >> 9) & 1;
        int kk = (i2 >> 10) & 7, tap = i2 >> 13;
        int o = mt * 16 + (l & 15);
        int c = kk * 32 + (l >> 4) * 8 + j;
        w2r[i2] = (o < 18) ? f2bf(w2[((size_t)o * 256 + c) * 9 + tap]) : 0;
    }
}

// ---- conv1 v2: col-space tiling, LDS B-window, writes featb directly -------
// Old conv1: 864 blocks x 768KB weight slice = 663MB weight traffic -> ~60us
// (same VMEM-address disease as old k_deform; ~1.4 lane-addr/cyc/CU cap).
// v2: 256 blocks = 32 px-tiles(72) x 2 b x 4 out-quarters(64 o). Each block
// stages its tap-shifted 80-row qkT window in LDS (80KB, OOB rows -> pad row
// zeros), sweeps all 9 taps x K=512. Weight traffic 663->144MB; lane-addrs
// ~86K/CU. Out-split -> no partials: adds b1, writes featb bf16 (k_fcast gone).
__global__ __launch_bounds__(256) void k_conv1(const unsigned short* __restrict__ qkT,
        const unsigned short* __restrict__ w1r, const float* __restrict__ b1,
        unsigned short* __restrict__ featb) {
    __shared__ __align__(16) unsigned short Bl[80 * 64 * 8];   // 80 rows x 1KB = 80KB

    const int tid = threadIdx.x;
    const int pt = blockIdx.x;            // 32 px-tiles of 72
    const int b  = blockIdx.y;
    const int oq = blockIdx.z;            // outs oq*64..+63
    const int px0 = pt * 72;
    const int lane = tid & 63, wv = tid >> 6;
    const int lo = lane & 15, quad = lane >> 4;
    const int mtg = oq * 4 + wv;          // this wave's 16-out group

    floatx4 acc[5];
#pragma unroll
    for (int nt = 0; nt < 5; nt++) acc[nt] = (floatx4)0.f;

    for (int tap = 0; tap < 9; tap++) {
        const int dy = tap / 3 - 1, dx = tap % 3 - 1;
        __syncthreads();                  // prev GEMM reads done before overwrite
#pragma unroll
        for (int k = 0; k < 20; k++) {
            int seg = tid + k * 256;      // 0..5119
            int cl  = seg >> 6;           // 0..79 (72..79 phantom)
            int sl  = seg & 63;           // 16B slot within row
            int px  = px0 + cl;
            int h = px / WW, w = px - (px / WW) * WW;
            bool val = (cl < 72) && (h + dy >= 0) && (h + dy < HH)
                       && (w + dx >= 0) && (w + dx < WW);
            int row = val ? (px + dy * WW + dx) : HWP;   // pad row = zeros
            short8 d = *(const short8*)(qkT + ((size_t)b * QKROW + row) * 512 + sl * 8);
            int slw = sl ^ (cl & 7);      // XOR bank swizzle
            *(short8*)(Bl + ((size_t)cl * 64 + slw) * 8) = d;
        }
        __syncthreads();

        const unsigned short* afr = w1r + (((size_t)tap * 16 * 16 + mtg) * 64 + lane) * 8;
#pragma unroll 4
        for (int ks = 0; ks < 16; ks++) {
            short8 a = *(const short8*)(afr + (size_t)ks * 16 * 512);
#pragma unroll
            for (int nt = 0; nt < 5; nt++) {
                int cl = nt * 16 + lo;
                int slot = (ks * 4 + quad) ^ (cl & 7);
                short8 bf = *(const short8*)(Bl + ((size_t)cl * 64 + slot) * 8);
                acc[nt] = __builtin_amdgcn_mfma_f32_16x16x32_bf16(a, bf, acc[nt], 0, 0, 0);
            }
        }
    }

    // epilogue: featb[b][px][o] = bf16(acc + b1[o]);  o = mtg*16 + quad*4 + i
    const int o = mtg * 16 + quad * 4;
    const float b0 = b1[o], bb1 = b1[o + 1], bb2 = b1[o + 2], bb3 = b1[o + 3];
#pragma unroll
    for (int nt = 0; nt < 5; nt++) {
        int cl = nt * 16 + lo;
        if (cl < 72) {
            int px = px0 + cl;
            bf16x4 pk;
            pk[0] = (short)f2bf(acc[nt][0] + b0);
            pk[1] = (short)f2bf(acc[nt][1] + bb1);
            pk[2] = (short)f2bf(acc[nt][2] + bb2);
            pk[3] = (short)f2bf(acc[nt][3] + bb3);
            *(bf16x4*)(featb + ((size_t)b * QKROW + px) * 256 + o) = pk;
        }
    }
}

// ---- conv2: tap-split(9) -> fp32 partials off9[t][b][px][32] ---------------
__global__ __launch_bounds__(256) void k_conv2(const unsigned short* __restrict__ featb,
        const unsigned short* __restrict__ w2r, float* __restrict__ off9) {
    const int tid = threadIdx.x;
    const int pb = blockIdx.x;            // 36
    const int b  = blockIdx.y;
    const int tap = blockIdx.z;
    const int lane = tid & 63, wv = tid >> 6;
    const int lo = lane & 15, quad = lane >> 4;
    const int pp = pb * 64 + wv * 16 + lo;
    const int h = pp / WW, w = pp - (pp / WW) * WW;
    const int dy = tap / 3 - 1, dx = tap % 3 - 1;
    const bool val = (h + dy >= 0) && (h + dy < HH) && (w + dx >= 0) && (w + dx < WW);
    const int row = val ? (pp + dy * WW + dx) : HWP;

    const unsigned short* brow = featb + ((size_t)b * QKROW + row) * 256 + quad * 8;
    const unsigned short* afr = w2r + (((size_t)tap * 8 * 2) * 64 + lane) * 8;

    floatx4 acc[2];
    acc[0] = (floatx4)0.f; acc[1] = (floatx4)0.f;
#pragma unroll
    for (int ks = 0; ks < 8; ks++) {
        short8 bf = *(const short8*)(brow + ks * 32);
        const unsigned short* ak = afr + (size_t)ks * 2 * 512;
        short8 a0 = *(const short8*)(ak);
        short8 a1 = *(const short8*)(ak + 512);
        acc[0] = __builtin_amdgcn_mfma_f32_16x16x32_bf16(a0, bf, acc[0], 0, 0, 0);
        acc[1] = __builtin_amdgcn_mfma_f32_16x16x32_bf16(a1, bf, acc[1], 0, 0, 0);
    }

    float* dst = off9 + (((size_t)tap * 2 + b) * HWP + pp) * 32;
#pragma unroll
    for (int mt = 0; mt < 2; mt++) {
        int o = mt * 16 + quad * 4;
        *(floatx4*)(dst + o) = acc[mt];
    }
}

// ---- osum: off[b][o][px] = sum_t off9 + b2[o]  (o<18) ----------------------
__global__ __launch_bounds__(256) void k_osum(const float* __restrict__ off9,
        const float* __restrict__ b2, float* __restrict__ off) {
    int i = blockIdx.x * 256 + threadIdx.x;        // < 2*18*2304
    int b = i / (18 * HWP);
    int r = i - b * 18 * HWP;
    int o = r / HWP, px = r - o * HWP;
    float s = b2[o];
#pragma unroll
    for (int t = 0; t < 9; t++)
        s += off9[(((size_t)t * 2 + b) * HWP + px) * 32 + o];
    off[i] = s;
}

// ---- deform: col-space tiling (col = pq*8+n), 256 blocks x 72 cols ---------
// (unchanged from round 6: 67.7us, VMEM-address-bound, verified)
__global__ __launch_bounds__(512, 2) void k_deform(const unsigned short* __restrict__ vT,
        const float* __restrict__ off, const unsigned short* __restrict__ wdr,
        const float* __restrict__ db, const float* __restrict__ q,
        float* __restrict__ out) {
    __shared__ __align__(16) unsigned short Sl[2][80 * 256];   // 2 x 40 KB

    const int tid = threadIdx.x;
    const int bid = blockIdx.x;                       // 256
    const int c0 = (((bid & 7) << 5) + (bid >> 3)) * 72;
    const int lane = tid & 63, wv = tid >> 6;
    const int lo = lane & 15, quad = lane >> 4;
    const int colg = tid >> 5;                        // 0..15 staging col group
    const int slice = tid & 31;                       // 8-ch (16B) slice

    int u_pq[5];
    float u_m[5];
    const float* u_off[5];
    const unsigned short* u_vT[5];
#pragma unroll
    for (int u = 0; u < 5; u++) {
        int cl = colg + u * 16;
        int cg = min(c0 + cl, 18431);
        int pq = cg >> 3, n = cg & 7;
        u_pq[u] = pq;
        u_m[u]  = (cl < 72) ? 1.f : 0.f;
        u_off[u] = off + (size_t)(n >> 2) * 18 * HWP + pq;
        u_vT[u]  = vT + (size_t)n * HWP * 256 + slice * 8;
    }

    floatx4 acc[2][5];
#pragma unroll
    for (int mt = 0; mt < 2; mt++)
#pragma unroll
        for (int nt = 0; nt < 5; nt++) acc[mt][nt] = (floatx4)0.f;

    short8 P[5][4];
    float  cwt[5][4];
    float  ndy[5], ndx[5];

    auto prefetch_off = [&](int tap) {
#pragma unroll
        for (int u = 0; u < 5; u++) {
            ndy[u] = u_off[u][(2 * tap) * HWP];
            ndx[u] = u_off[u][(2 * tap + 1) * HWP];
        }
    };

    auto prefetch_body = [&](int tap) {
        const float kdy = (float)(tap / 3 - 1), kdx = (float)(tap % 3 - 1);
#pragma unroll
        for (int u = 0; u < 5; u++) {
            int pq = u_pq[u];
            int h = pq / WW, w = pq - (pq / WW) * WW;
            float py = ndy[u] + (float)h + kdy;
            float px = ndx[u] + (float)w + kdx;
            float y0f = floorf(py), x0f = floorf(px);
            int y0 = (int)y0f, x0 = (int)x0f;
            float fy = py - y0f, fx = px - x0f;
            bool y0ok = (y0 >= 0) & (y0 < HH), y1ok = (y0 >= -1) & (y0 < HH - 1);
            bool x0ok = (x0 >= 0) & (x0 < WW), x1ok = (x0 >= -1) & (x0 < WW - 1);
            int y0c = min(max(y0, 0), HH - 1), y1c = min(max(y0 + 1, 0), HH - 1);
            int x0c = min(max(x0, 0), WW - 1), x1c = min(max(x0 + 1, 0), WW - 1);
            const unsigned short* r0 = u_vT[u] + (size_t)(y0c * WW + x0c) * 256;
            const unsigned short* r1 = u_vT[u] + (size_t)(y0c * WW + x1c) * 256;
            const unsigned short* r2 = u_vT[u] + (size_t)(y1c * WW + x0c) * 256;
            const unsigned short* r3 = u_vT[u] + (size_t)(y1c * WW + x1c) * 256;
            float m = u_m[u];
            cwt[u][0] = (y0ok && x0ok) ? m * (1.f - fy) * (1.f - fx) : 0.f;
            cwt[u][1] = (y0ok && x1ok) ? m * (1.f - fy) * fx         : 0.f;
            cwt[u][2] = (y1ok && x0ok) ? m * fy * (1.f - fx)         : 0.f;
            cwt[u][3] = (y1ok && x1ok) ? m * fy * fx                 : 0.f;
            P[u][0] = *(const short8*)(r0);
            P[u][1] = *(const short8*)(r1);
            P[u][2] = *(const short8*)(r2);
            P[u][3] = *(const short8*)(r3);
        }
    };

    prefetch_off(0);
    prefetch_body(0);
    int buf = 0;

    for (int tap = 0; tap < 9; tap++) {
        if (tap < 8) prefetch_off(tap + 1);
        unsigned short* sb = &Sl[buf][0];
#pragma unroll
        for (int u = 0; u < 5; u++) {
            float w0 = cwt[u][0], w1 = cwt[u][1], w2 = cwt[u][2], w3 = cwt[u][3];
            short8 ov;
#pragma unroll
            for (int j = 0; j < 8; j++) {
                float s = w0 * bf2f(P[u][0][j]) + w1 * bf2f(P[u][1][j])
                        + w2 * bf2f(P[u][2][j]) + w3 * bf2f(P[u][3][j]);
                ov[j] = (short)f2bf(s);
            }
            int cl = colg + u * 16;
            int slot = slice ^ (cl & 7);
            *(short8*)(sb + cl * 256 + slot * 8) = ov;
        }
        __syncthreads();

        if (tap < 8) prefetch_body(tap + 1);

        const unsigned short* afr = wdr + (((size_t)tap * 8 * 16 + wv * 2) * 64 + lane) * 8;
#pragma unroll
        for (int ks = 0; ks < 8; ks++) {
            const unsigned short* ak = afr + (size_t)ks * 16 * 512;
            short8 a0 = *(const short8*)(ak);
            short8 a1 = *(const short8*)(ak + 512);
#pragma unroll
            for (int nt = 0; nt < 5; nt++) {
                int cl = nt * 16 + lo;
                int slot = (ks * 4 + quad) ^ (cl & 7);
                short8 bf = *(const short8*)(sb + cl * 256 + slot * 8);
                acc[0][nt] = __builtin_amdgcn_mfma_f32_16x16x32_bf16(a0, bf, acc[0][nt], 0, 0, 0);
                acc[1][nt] = __builtin_amdgcn_mfma_f32_16x16x32_bf16(a1, bf, acc[1][nt], 0, 0, 0);
            }
        }
        __syncthreads();
        buf ^= 1;
    }

#pragma unroll
    for (int mt = 0; mt < 2; mt++) {
        int o = wv * 32 + mt * 16 + quad * 4;
        float d0 = db[o], d1 = db[o + 1], d2 = db[o + 2], d3 = db[o + 3];
#pragma unroll
        for (int nt = 0; nt < 5; nt++) {
            int cl = nt * 16 + lo;
            if (cl < 72) {
                int cg = c0 + cl;
                int pq = cg >> 3, b = (cg & 7) >> 2;
                floatx4 r = acc[mt][nt];
                r[0] += d0 + q[((size_t)b * CC + o + 0) * HWP + pq];
                r[1] += d1 + q[((size_t)b * CC + o + 1) * HWP + pq];
                r[2] += d2 + q[((size_t)b * CC + o + 2) * HWP + pq];
                r[3] += d3 + q[((size_t)b * CC + o + 3) * HWP + pq];
                *(floatx4*)(out + (size_t)cg * CC + o) = r;
            }
        }
    }
}

extern "C" void kernel_launch(void* const* d_in, const int* in_sizes, int n_in,
                              void* d_out, int out_size, void* d_ws, size_t ws_size,
                              hipStream_t stream) {
    const float* q  = (const float*)d_in[0];
    const float* k  = (const float*)d_in[1];
    const float* v  = (const float*)d_in[2];
    const float* w1 = (const float*)d_in[3];
    const float* b1 = (const float*)d_in[4];
    const float* w2 = (const float*)d_in[5];
    const float* b2 = (const float*)d_in[6];
    const float* dw = (const float*)d_in[7];
    const float* db = (const float*)d_in[8];
    float* out = (float*)d_out;

    // ws layout (~40 MB): off | feat3(now unused) | off9 (fp32) || qkT | vT | featb | w1r | wdr | w2r
    float* off   = (float*)d_ws;                          //    82,944 f
    float* feat3 = off + 82944;                           // 3,538,944 f (dead)
    float* off9  = feat3 + 3538944;                       // 1,327,104 f
    unsigned short* qkT   = (unsigned short*)(off9 + 1327104);
    unsigned short* vT    = qkT + 2360320;                // 2*2305*512
    unsigned short* featb = vT + 4718592;                 // 2*2305*256
    unsigned short* w1r   = featb + 1180160;              // frag order
    unsigned short* wdr   = w1r + 1179648;
    unsigned short* w2r   = wdr + 589824;

    hipLaunchKernelGGL(k_tr_qk, dim3(36, 4, 4),  dim3(256), 0, stream, q, k, qkT);
    hipLaunchKernelGGL(k_tr_v,  dim3(36, 4, 8),  dim3(256), 0, stream, v, vT);
    hipLaunchKernelGGL(k_prep_w,dim3(7201),      dim3(256), 0, stream, w1, dw, w2, w1r, wdr, w2r, qkT, featb);
    hipLaunchKernelGGL(k_conv1, dim3(32, 2, 4),  dim3(256), 0, stream, qkT, w1r, b1, featb);
    hipLaunchKernelGGL(k_conv2, dim3(36, 2, 9),  dim3(256), 0, stream, featb, w2r, off9);
    hipLaunchKernelGGL(k_osum,  dim3(324),       dim3(256), 0, stream, off9, b2, off);
    hipLaunchKernelGGL(k_deform,dim3(256),       dim3(512), 0, stream, vT, off, wdr, db, q, out);
}

// Round 9
// 208.543 us; speedup vs baseline: 1.2055x; 1.2055x over previous
//
#include <hip/hip_runtime.h>

// Problem constants: B=2, obj=4, C=256, H=W=48, N=8, HW=2304
#define HH 48
#define WW 48
#define HWP 2304
#define CC 256
#define NB 8
#define QKROW 2305   // 2304 rows + 1 zero pad row (index 2304) for OOB taps

typedef __attribute__((ext_vector_type(8))) short short8;   // 8 x bf16 = 4 VGPR
typedef __attribute__((ext_vector_type(4))) short bf16x4;   // 4 x bf16 = 8B
typedef __attribute__((ext_vector_type(4))) float floatx4;  // MFMA C/D frag

static __device__ __forceinline__ unsigned short f2bf(float f) {
    union { float f; unsigned u; } v; v.f = f;
    unsigned r = v.u + 0x7fffu + ((v.u >> 16) & 1u);        // RNE
    return (unsigned short)(r >> 16);
}
static __device__ __forceinline__ float bf2f(short v) {
    union { unsigned u; float f; } x; x.u = ((unsigned)(unsigned short)v) << 16;
    return x.f;
}

// ---- tiled transpose q/k -> qkT[b][px][c2] bf16 (64x64 tiles via LDS) ------
__global__ __launch_bounds__(256) void k_tr_qk(const float* __restrict__ q,
        const float* __restrict__ kk, unsigned short* __restrict__ qkT) {
    __shared__ float T[64][65];
    const int pg = blockIdx.x, cg = blockIdx.y;
    const int b = blockIdx.z >> 1, src = blockIdx.z & 1;
    const float* s = (src ? kk : q) + (size_t)b * CC * HWP;
    const int tx = threadIdx.x & 63, ty = threadIdx.x >> 6;
#pragma unroll
    for (int i = 0; i < 16; i++) {
        int cl = ty * 16 + i;
        T[cl][tx] = s[(size_t)(cg * 64 + cl) * HWP + pg * 64 + tx];
    }
    __syncthreads();
#pragma unroll
    for (int i = 0; i < 16; i++) {
        int pxl = ty * 16 + i;
        qkT[((size_t)b * QKROW + pg * 64 + pxl) * 512 + src * 256 + cg * 64 + tx]
            = f2bf(T[tx][pxl]);
    }
}

// ---- tiled transpose value -> vT[n][px][c] bf16 ----------------------------
__global__ __launch_bounds__(256) void k_tr_v(const float* __restrict__ v,
                                              unsigned short* __restrict__ vT) {
    __shared__ float T[64][65];
    const int pg = blockIdx.x, cg = blockIdx.y, n = blockIdx.z;
    const float* s = v + (size_t)n * CC * HWP;
    const int tx = threadIdx.x & 63, ty = threadIdx.x >> 6;
#pragma unroll
    for (int i = 0; i < 16; i++) {
        int cl = ty * 16 + i;
        T[cl][tx] = s[(size_t)(cg * 64 + cl) * HWP + pg * 64 + tx];
    }
    __syncthreads();
#pragma unroll
    for (int i = 0; i < 16; i++) {
        int pxl = ty * 16 + i;
        vT[((size_t)n * HWP + pg * 64 + pxl) * 256 + cg * 64 + tx] = f2bf(T[tx][pxl]);
    }
}

// ---- weight preshuffle into MFMA-fragment order (1KB contiguous frags) -----
// A-operand lane map (16x16x32): lane l holds A[m = l&15][k = (l>>4)*8 + j].
// w1r:  [tap(9)][kk(16)][mtg(16)][l(64)][j(8)]
// wdr:  [tap(9)][kk(8)] [mtg(16)][l(64)][j(8)]
// w2r:  [tap(9)][kk(8)] [mt(2)]  [l(64)][j(8)]   (rows o>=18 zero)
// Last block (7200) zeroes the qkT and featb pad rows (was k_pads).
__global__ __launch_bounds__(256) void k_prep_w(const float* __restrict__ w1,
        const float* __restrict__ dw, const float* __restrict__ w2,
        unsigned short* __restrict__ w1r, unsigned short* __restrict__ wdr,
        unsigned short* __restrict__ w2r, unsigned short* __restrict__ qkT,
        unsigned short* __restrict__ featb) {
    if (blockIdx.x == 7200) {
        int t = threadIdx.x;
#pragma unroll
        for (int b = 0; b < 2; b++) {
            qkT[((size_t)b * QKROW + HWP) * 512 + t] = 0;
            qkT[((size_t)b * QKROW + HWP) * 512 + 256 + t] = 0;
            featb[((size_t)b * QKROW + HWP) * 256 + t] = 0;
        }
        return;
    }
    int idx = blockIdx.x * 256 + threadIdx.x;
    if (idx < 1179648) {
        int j = idx & 7, l = (idx >> 3) & 63, mtg = (idx >> 9) & 15;
        int kk = (idx >> 13) & 15, tap = idx >> 17;
        int o = mtg * 16 + (l & 15);
        int c2 = kk * 32 + (l >> 4) * 8 + j;
        w1r[idx] = f2bf(w1[((size_t)o * 512 + c2) * 9 + tap]);
    } else if (idx < 1179648 + 589824) {
        int i2 = idx - 1179648;
        int j = i2 & 7, l = (i2 >> 3) & 63, mtg = (i2 >> 9) & 15;
        int kk = (i2 >> 13) & 7, tap = i2 >> 16;
        int o = mtg * 16 + (l & 15);
        int c = kk * 32 + (l >> 4) * 8 + j;
        wdr[i2] = f2bf(dw[((size_t)o * 256 + c) * 9 + tap]);
    } else {
        int i2 = idx - 1179648 - 589824;
        int j = i2 & 7, l = (i2 >> 3) & 63, mt = (i2 >> 9) & 1;
        int kk = (i2 >> 10) & 7, tap = i2 >> 13;
        int o = mt * 16 + (l & 15);
        int c = kk * 32 + (l >> 4) * 8 + j;
        w2r[i2] = (o < 18) ? f2bf(w2[((size_t)o * 256 + c) * 9 + tap]) : 0;
    }
}

// ---- conv1 v3: k_deform-structure port ------------------------------------
// v2 (73us) had the tiling but not the OVERLAP: 256thr/4waves, staging fully
// exposed between barriers -> 0.47 addr/cyc vs deform's 1.46. v3 mirrors
// deform: 512 thr (8 waves), px-tile 32 (no phantoms), 2x32KB LDS dbuf ->
// 2 blocks/CU, reg-prefetch of next tap's 4 staging loads issued right after
// the single per-tap barrier so they land under the GEMM. ~104K lane-addrs/CU
// -> ~30us at the demonstrated address throughput. Weights (332MB re-read)
// are L2-resident (w1r = 2.25MB per XCD L2).
__global__ __launch_bounds__(512, 4) void k_conv1(const unsigned short* __restrict__ qkT,
        const unsigned short* __restrict__ w1r, const float* __restrict__ b1,
        unsigned short* __restrict__ featb) {
    __shared__ __align__(16) unsigned short Bl[2][32 * 64 * 8];   // 2 x 32 KB

    const int tid = threadIdx.x;          // 0..511
    const int pt = blockIdx.x;            // 72 px-tiles of 32
    const int b  = blockIdx.y;
    const int oh = blockIdx.z;            // out half (128 outs)
    const int px0 = pt * 32;
    const int lane = tid & 63, wv = tid >> 6;   // 8 waves
    const int lo = lane & 15, quad = lane >> 4;
    const int mtg = oh * 8 + wv;          // this wave's 16-out group

    floatx4 acc[2];
    acc[0] = (floatx4)0.f; acc[1] = (floatx4)0.f;

    short8 R[4];                          // prefetched staging rows (next tap)
    auto stage_load = [&](int tap) {
        const int dy = tap / 3 - 1, dx = tap % 3 - 1;
#pragma unroll
        for (int k = 0; k < 4; k++) {
            int seg = tid + k * 512;      // 0..2047
            int cl  = seg >> 6;           // LDS row = output px0+cl
            int sl  = seg & 63;           // 16B slot within 512-ch row
            int px  = px0 + cl;
            int h = px / WW, w = px - (px / WW) * WW;
            bool val = (h + dy >= 0) && (h + dy < HH)
                       && (w + dx >= 0) && (w + dx < WW);
            int row = val ? (px + dy * WW + dx) : HWP;   // pad row = zeros
            R[k] = *(const short8*)(qkT + ((size_t)b * QKROW + row) * 512 + sl * 8);
        }
    };

    stage_load(0);
    int buf = 0;

    for (int tap = 0; tap < 9; tap++) {
        unsigned short* sb = &Bl[buf][0];
#pragma unroll
        for (int k = 0; k < 4; k++) {
            int seg = tid + k * 512;
            int cl = seg >> 6, sl = seg & 63;
            int slw = sl ^ (cl & 7);      // XOR bank swizzle
            *(short8*)(sb + ((size_t)cl * 64 + slw) * 8) = R[k];
        }
        __syncthreads();                  // dbuf: single barrier per tap is safe

        if (tap < 8) stage_load(tap + 1); // loads land during GEMM below

        const unsigned short* afr = w1r + (((size_t)tap * 16 * 16 + mtg) * 64 + lane) * 8;
#pragma unroll 4
        for (int ks = 0; ks < 16; ks++) {
            short8 a = *(const short8*)(afr + (size_t)ks * 16 * 512);
#pragma unroll
            for (int nt = 0; nt < 2; nt++) {
                int cl = nt * 16 + lo;
                int slot = (ks * 4 + quad) ^ (cl & 7);
                short8 bf = *(const short8*)(sb + ((size_t)cl * 64 + slot) * 8);
                acc[nt] = __builtin_amdgcn_mfma_f32_16x16x32_bf16(a, bf, acc[nt], 0, 0, 0);
            }
        }
        buf ^= 1;
    }

    // epilogue: featb[b][px][o] = bf16(acc + b1[o]);  o = mtg*16 + quad*4 + i
    const int o = mtg * 16 + quad * 4;
    const float b0 = b1[o], bb1 = b1[o + 1], bb2 = b1[o + 2], bb3 = b1[o + 3];
#pragma unroll
    for (int nt = 0; nt < 2; nt++) {
        int px = px0 + nt * 16 + lo;
        bf16x4 pk;
        pk[0] = (short)f2bf(acc[nt][0] + b0);
        pk[1] = (short)f2bf(acc[nt][1] + bb1);
        pk[2] = (short)f2bf(acc[nt][2] + bb2);
        pk[3] = (short)f2bf(acc[nt][3] + bb3);
        *(bf16x4*)(featb + ((size_t)b * QKROW + px) * 256 + o) = pk;
    }
}

// ---- conv2: tap-split(9) -> fp32 partials off9[t][b][px][32] ---------------
__global__ __launch_bounds__(256) void k_conv2(const unsigned short* __restrict__ featb,
        const unsigned short* __restrict__ w2r, float* __restrict__ off9) {
    const int tid = threadIdx.x;
    const int pb = blockIdx.x;            // 36
    const int b  = blockIdx.y;
    const int tap = blockIdx.z;
    const int lane = tid & 63, wv = tid >> 6;
    const int lo = lane & 15, quad = lane >> 4;
    const int pp = pb * 64 + wv * 16 + lo;
    const int h = pp / WW, w = pp - (pp / WW) * WW;
    const int dy = tap / 3 - 1, dx = tap % 3 - 1;
    const bool val = (h + dy >= 0) && (h + dy < HH) && (w + dx >= 0) && (w + dx < WW);
    const int row = val ? (pp + dy * WW + dx) : HWP;

    const unsigned short* brow = featb + ((size_t)b * QKROW + row) * 256 + quad * 8;
    const unsigned short* afr = w2r + (((size_t)tap * 8 * 2) * 64 + lane) * 8;

    floatx4 acc[2];
    acc[0] = (floatx4)0.f; acc[1] = (floatx4)0.f;
#pragma unroll
    for (int ks = 0; ks < 8; ks++) {
        short8 bf = *(const short8*)(brow + ks * 32);
        const unsigned short* ak = afr + (size_t)ks * 2 * 512;
        short8 a0 = *(const short8*)(ak);
        short8 a1 = *(const short8*)(ak + 512);
        acc[0] = __builtin_amdgcn_mfma_f32_16x16x32_bf16(a0, bf, acc[0], 0, 0, 0);
        acc[1] = __builtin_amdgcn_mfma_f32_16x16x32_bf16(a1, bf, acc[1], 0, 0, 0);
    }

    float* dst = off9 + (((size_t)tap * 2 + b) * HWP + pp) * 32;
#pragma unroll
    for (int mt = 0; mt < 2; mt++) {
        int o = mt * 16 + quad * 4;
        *(floatx4*)(dst + o) = acc[mt];
    }
}

// ---- osum: off[b][o][px] = sum_t off9 + b2[o]  (o<18) ----------------------
__global__ __launch_bounds__(256) void k_osum(const float* __restrict__ off9,
        const float* __restrict__ b2, float* __restrict__ off) {
    int i = blockIdx.x * 256 + threadIdx.x;        // < 2*18*2304
    int b = i / (18 * HWP);
    int r = i - b * 18 * HWP;
    int o = r / HWP, px = r - o * HWP;
    float s = b2[o];
#pragma unroll
    for (int t = 0; t < 9; t++)
        s += off9[(((size_t)t * 2 + b) * HWP + px) * 32 + o];
    off[i] = s;
}

// ---- deform: col-space tiling (col = pq*8+n), 256 blocks x 72 cols ---------
// (unchanged from round 6: 67.7us, VMEM-address-bound, verified)
__global__ __launch_bounds__(512, 2) void k_deform(const unsigned short* __restrict__ vT,
        const float* __restrict__ off, const unsigned short* __restrict__ wdr,
        const float* __restrict__ db, const float* __restrict__ q,
        float* __restrict__ out) {
    __shared__ __align__(16) unsigned short Sl[2][80 * 256];   // 2 x 40 KB

    const int tid = threadIdx.x;
    const int bid = blockIdx.x;                       // 256
    const int c0 = (((bid & 7) << 5) + (bid >> 3)) * 72;
    const int lane = tid & 63, wv = tid >> 6;
    const int lo = lane & 15, quad = lane >> 4;
    const int colg = tid >> 5;                        // 0..15 staging col group
    const int slice = tid & 31;                       // 8-ch (16B) slice

    int u_pq[5];
    float u_m[5];
    const float* u_off[5];
    const unsigned short* u_vT[5];
#pragma unroll
    for (int u = 0; u < 5; u++) {
        int cl = colg + u * 16;
        int cg = min(c0 + cl, 18431);
        int pq = cg >> 3, n = cg & 7;
        u_pq[u] = pq;
        u_m[u]  = (cl < 72) ? 1.f : 0.f;
        u_off[u] = off + (size_t)(n >> 2) * 18 * HWP + pq;
        u_vT[u]  = vT + (size_t)n * HWP * 256 + slice * 8;
    }

    floatx4 acc[2][5];
#pragma unroll
    for (int mt = 0; mt < 2; mt++)
#pragma unroll
        for (int nt = 0; nt < 5; nt++) acc[mt][nt] = (floatx4)0.f;

    short8 P[5][4];
    float  cwt[5][4];
    float  ndy[5], ndx[5];

    auto prefetch_off = [&](int tap) {
#pragma unroll
        for (int u = 0; u < 5; u++) {
            ndy[u] = u_off[u][(2 * tap) * HWP];
            ndx[u] = u_off[u][(2 * tap + 1) * HWP];
        }
    };

    auto prefetch_body = [&](int tap) {
        const float kdy = (float)(tap / 3 - 1), kdx = (float)(tap % 3 - 1);
#pragma unroll
        for (int u = 0; u < 5; u++) {
            int pq = u_pq[u];
            int h = pq / WW, w = pq - (pq / WW) * WW;
            float py = ndy[u] + (float)h + kdy;
            float px = ndx[u] + (float)w + kdx;
            float y0f = floorf(py), x0f = floorf(px);
            int y0 = (int)y0f, x0 = (int)x0f;
            float fy = py - y0f, fx = px - x0f;
            bool y0ok = (y0 >= 0) & (y0 < HH), y1ok = (y0 >= -1) & (y0 < HH - 1);
            bool x0ok = (x0 >= 0) & (x0 < WW), x1ok = (x0 >= -1) & (x0 < WW - 1);
            int y0c = min(max(y0, 0), HH - 1), y1c = min(max(y0 + 1, 0), HH - 1);
            int x0c = min(max(x0, 0), WW - 1), x1c = min(max(x0 + 1, 0), WW - 1);
            const unsigned short* r0 = u_vT[u] + (size_t)(y0c * WW + x0c) * 256;
            const unsigned short* r1 = u_vT[u] + (size_t)(y0c * WW + x1c) * 256;
            const unsigned short* r2 = u_vT[u] + (size_t)(y1c * WW + x0c) * 256;
            const unsigned short* r3 = u_vT[u] + (size_t)(y1c * WW + x1c) * 256;
            float m = u_m[u];
            cwt[u][0] = (y0ok && x0ok) ? m * (1.f - fy) * (1.f - fx) : 0.f;
            cwt[u][1] = (y0ok && x1ok) ? m * (1.f - fy) * fx         : 0.f;
            cwt[u][2] = (y1ok && x0ok) ? m * fy * (1.f - fx)         : 0.f;
            cwt[u][3] = (y1ok && x1ok) ? m * fy * fx                 : 0.f;
            P[u][0] = *(const short8*)(r0);
            P[u][1] = *(const short8*)(r1);
            P[u][2] = *(const short8*)(r2);
            P[u][3] = *(const short8*)(r3);
        }
    };

    prefetch_off(0);
    prefetch_body(0);
    int buf = 0;

    for (int tap = 0; tap < 9; tap++) {
        if (tap < 8) prefetch_off(tap + 1);
        unsigned short* sb = &Sl[buf][0];
#pragma unroll
        for (int u = 0; u < 5; u++) {
            float w0 = cwt[u][0], w1 = cwt[u][1], w2 = cwt[u][2], w3 = cwt[u][3];
            short8 ov;
#pragma unroll
            for (int j = 0; j < 8; j++) {
                float s = w0 * bf2f(P[u][0][j]) + w1 * bf2f(P[u][1][j])
                        + w2 * bf2f(P[u][2][j]) + w3 * bf2f(P[u][3][j]);
                ov[j] = (short)f2bf(s);
            }
            int cl = colg + u * 16;
            int slot = slice ^ (cl & 7);
            *(short8*)(sb + cl * 256 + slot * 8) = ov;
        }
        __syncthreads();

        if (tap < 8) prefetch_body(tap + 1);

        const unsigned short* afr = wdr + (((size_t)tap * 8 * 16 + wv * 2) * 64 + lane) * 8;
#pragma unroll
        for (int ks = 0; ks < 8; ks++) {
            const unsigned short* ak = afr + (size_t)ks * 16 * 512;
            short8 a0 = *(const short8*)(ak);
            short8 a1 = *(const short8*)(ak + 512);
#pragma unroll
            for (int nt = 0; nt < 5; nt++) {
                int cl = nt * 16 + lo;
                int slot = (ks * 4 + quad) ^ (cl & 7);
                short8 bf = *(const short8*)(sb + cl * 256 + slot * 8);
                acc[0][nt] = __builtin_amdgcn_mfma_f32_16x16x32_bf16(a0, bf, acc[0][nt], 0, 0, 0);
                acc[1][nt] = __builtin_amdgcn_mfma_f32_16x16x32_bf16(a1, bf, acc[1][nt], 0, 0, 0);
            }
        }
        __syncthreads();
        buf ^= 1;
    }

#pragma unroll
    for (int mt = 0; mt < 2; mt++) {
        int o = wv * 32 + mt * 16 + quad * 4;
        float d0 = db[o], d1 = db[o + 1], d2 = db[o + 2], d3 = db[o + 3];
#pragma unroll
        for (int nt = 0; nt < 5; nt++) {
            int cl = nt * 16 + lo;
            if (cl < 72) {
                int cg = c0 + cl;
                int pq = cg >> 3, b = (cg & 7) >> 2;
                floatx4 r = acc[mt][nt];
                r[0] += d0 + q[((size_t)b * CC + o + 0) * HWP + pq];
                r[1] += d1 + q[((size_t)b * CC + o + 1) * HWP + pq];
                r[2] += d2 + q[((size_t)b * CC + o + 2) * HWP + pq];
                r[3] += d3 + q[((size_t)b * CC + o + 3) * HWP + pq];
                *(floatx4*)(out + (size_t)cg * CC + o) = r;
            }
        }
    }
}

extern "C" void kernel_launch(void* const* d_in, const int* in_sizes, int n_in,
                              void* d_out, int out_size, void* d_ws, size_t ws_size,
                              hipStream_t stream) {
    const float* q  = (const float*)d_in[0];
    const float* k  = (const float*)d_in[1];
    const float* v  = (const float*)d_in[2];
    const float* w1 = (const float*)d_in[3];
    const float* b1 = (const float*)d_in[4];
    const float* w2 = (const float*)d_in[5];
    const float* b2 = (const float*)d_in[6];
    const float* dw = (const float*)d_in[7];
    const float* db = (const float*)d_in[8];
    float* out = (float*)d_out;

    // ws layout (~40 MB): off | feat3(unused) | off9 (fp32) || qkT | vT | featb | w1r | wdr | w2r
    float* off   = (float*)d_ws;                          //    82,944 f
    float* feat3 = off + 82944;                           // 3,538,944 f (dead)
    float* off9  = feat3 + 3538944;                       // 1,327,104 f
    unsigned short* qkT   = (unsigned short*)(off9 + 1327104);
    unsigned short* vT    = qkT + 2360320;                // 2*2305*512
    unsigned short* featb = vT + 4718592;                 // 2*2305*256
    unsigned short* w1r   = featb + 1180160;              // frag order
    unsigned short* wdr   = w1r + 1179648;
    unsigned short* w2r   = wdr + 589824;

    hipLaunchKernelGGL(k_tr_qk, dim3(36, 4, 4),  dim3(256), 0, stream, q, k, qkT);
    hipLaunchKernelGGL(k_tr_v,  dim3(36, 4, 8),  dim3(256), 0, stream, v, vT);
    hipLaunchKernelGGL(k_prep_w,dim3(7201),      dim3(256), 0, stream, w1, dw, w2, w1r, wdr, w2r, qkT, featb);
    hipLaunchKernelGGL(k_conv1, dim3(72, 2, 2),  dim3(512), 0, stream, qkT, w1r, b1, featb);
    hipLaunchKernelGGL(k_conv2, dim3(36, 2, 9),  dim3(256), 0, stream, featb, w2r, off9);
    hipLaunchKernelGGL(k_osum,  dim3(324),       dim3(256), 0, stream, off9, b2, off);
    hipLaunchKernelGGL(k_deform,dim3(256),       dim3(512), 0, stream, vT, off, wdr, db, q, out);
}

// Round 11
// 207.282 us; speedup vs baseline: 1.2128x; 1.0061x over previous
//
#include <hip/hip_runtime.h>

// Problem constants: B=2, obj=4, C=256, H=W=48, N=8, HW=2304
#define HH 48
#define WW 48
#define HWP 2304
#define CC 256
#define NB 8
#define QKROW 2305   // 2304 rows + 1 zero pad row (index 2304) for OOB taps

typedef __attribute__((ext_vector_type(8))) short short8;   // 8 x bf16 = 4 VGPR
typedef __attribute__((ext_vector_type(4))) short bf16x4;   // 4 x bf16 = 8B
typedef __attribute__((ext_vector_type(4))) float floatx4;  // MFMA C/D frag

static __device__ __forceinline__ unsigned short f2bf(float f) {
    union { float f; unsigned u; } v; v.f = f;
    unsigned r = v.u + 0x7fffu + ((v.u >> 16) & 1u);        // RNE
    return (unsigned short)(r >> 16);
}
static __device__ __forceinline__ float bf2f(short v) {
    union { unsigned u; float f; } x; x.u = ((unsigned)(unsigned short)v) << 16;
    return x.f;
}

// ---- merged transposes: z<4 -> q/k -> qkT (+qT f32); z>=4 -> v -> vT -------
// qT[px][b][c] f32 feeds k_deform's epilogue as one floatx4 load.
__global__ __launch_bounds__(256) void k_tr(const float* __restrict__ q,
        const float* __restrict__ kk, const float* __restrict__ v,
        unsigned short* __restrict__ qkT, float* __restrict__ qT,
        unsigned short* __restrict__ vT) {
    __shared__ float T[64][65];
    const int pg = blockIdx.x, cg = blockIdx.y, z = blockIdx.z;
    const int tx = threadIdx.x & 63, ty = threadIdx.x >> 6;
    if (z < 4) {
        const int b = z >> 1, src = z & 1;
        const float* s = (src ? kk : q) + (size_t)b * CC * HWP;
#pragma unroll
        for (int i = 0; i < 16; i++) {
            int cl = ty * 16 + i;
            T[cl][tx] = s[(size_t)(cg * 64 + cl) * HWP + pg * 64 + tx];
        }
        __syncthreads();
#pragma unroll
        for (int i = 0; i < 16; i++) {
            int pxl = ty * 16 + i;
            float val = T[tx][pxl];
            qkT[((size_t)b * QKROW + pg * 64 + pxl) * 512 + src * 256 + cg * 64 + tx]
                = f2bf(val);
            if (src == 0)
                qT[((size_t)(pg * 64 + pxl) * 2 + b) * 256 + cg * 64 + tx] = val;
        }
    } else {
        const int n = z - 4;
        const float* s = v + (size_t)n * CC * HWP;
#pragma unroll
        for (int i = 0; i < 16; i++) {
            int cl = ty * 16 + i;
            T[cl][tx] = s[(size_t)(cg * 64 + cl) * HWP + pg * 64 + tx];
        }
        __syncthreads();
#pragma unroll
        for (int i = 0; i < 16; i++) {
            int pxl = ty * 16 + i;
            vT[((size_t)n * HWP + pg * 64 + pxl) * 256 + cg * 64 + tx] = f2bf(T[tx][pxl]);
        }
    }
}

// ---- weight preshuffle into MFMA-fragment order (1KB contiguous frags) -----
// A-operand lane map (16x16x32): lane l holds A[m = l&15][k = (l>>4)*8 + j].
// w1r:  [tap(9)][kk(16)][mtg(16)][l(64)][j(8)]
// wdr:  [tap(9)][kk(8)] [mtg(16)][l(64)][j(8)]
// w2r:  [tap(9)][kk(8)] [mt(2)]  [l(64)][j(8)]   (rows o>=18 zero)
// Last block (7200) zeroes the qkT and featb pad rows.
__global__ __launch_bounds__(256) void k_prep_w(const float* __restrict__ w1,
        const float* __restrict__ dw, const float* __restrict__ w2,
        unsigned short* __restrict__ w1r, unsigned short* __restrict__ wdr,
        unsigned short* __restrict__ w2r, unsigned short* __restrict__ qkT,
        unsigned short* __restrict__ featb) {
    if (blockIdx.x == 7200) {
        int t = threadIdx.x;
#pragma unroll
        for (int b = 0; b < 2; b++) {
            qkT[((size_t)b * QKROW + HWP) * 512 + t] = 0;
            qkT[((size_t)b * QKROW + HWP) * 512 + 256 + t] = 0;
            featb[((size_t)b * QKROW + HWP) * 256 + t] = 0;
        }
        return;
    }
    int idx = blockIdx.x * 256 + threadIdx.x;
    if (idx < 1179648) {
        int j = idx & 7, l = (idx >> 3) & 63, mtg = (idx >> 9) & 15;
        int kk = (idx >> 13) & 15, tap = idx >> 17;
        int o = mtg * 16 + (l & 15);
        int c2 = kk * 32 + (l >> 4) * 8 + j;
        w1r[idx] = f2bf(w1[((size_t)o * 512 + c2) * 9 + tap]);
    } else if (idx < 1179648 + 589824) {
        int i2 = idx - 1179648;
        int j = i2 & 7, l = (i2 >> 3) & 63, mtg = (i2 >> 9) & 15;
        int kk = (i2 >> 13) & 7, tap = i2 >> 16;
        int o = mtg * 16 + (l & 15);
        int c = kk * 32 + (l >> 4) * 8 + j;
        wdr[i2] = f2bf(dw[((size_t)o * 256 + c) * 9 + tap]);
    } else {
        int i2 = idx - 1179648 - 589824;
        int j = i2 & 7, l = (i2 >> 3) & 63, mt = (i2 >> 9) & 1;
        int kk = (i2 >> 10) & 7, tap = i2 >> 13;
        int o = mt * 16 + (l & 15);
        int c = kk * 32 + (l >> 4) * 8 + j;
        w2r[i2] = (o < 18) ? f2bf(w2[((size_t)o * 256 + c) * 9 + tap]) : 0;
    }
}

// ---- conv1 v3: k_deform-structure port (verified round 9, ~30us) -----------
__global__ __launch_bounds__(512, 4) void k_conv1(const unsigned short* __restrict__ qkT,
        const unsigned short* __restrict__ w1r, const float* __restrict__ b1,
        unsigned short* __restrict__ featb) {
    __shared__ __align__(16) unsigned short Bl[2][32 * 64 * 8];   // 2 x 32 KB

    const int tid = threadIdx.x;          // 0..511
    const int pt = blockIdx.x;            // 72 px-tiles of 32
    const int b  = blockIdx.y;
    const int oh = blockIdx.z;            // out half (128 outs)
    const int px0 = pt * 32;
    const int lane = tid & 63, wv = tid >> 6;   // 8 waves
    const int lo = lane & 15, quad = lane >> 4;
    const int mtg = oh * 8 + wv;          // this wave's 16-out group

    floatx4 acc[2];
    acc[0] = (floatx4)0.f; acc[1] = (floatx4)0.f;

    short8 R[4];                          // prefetched staging rows (next tap)
    auto stage_load = [&](int tap) {
        const int dy = tap / 3 - 1, dx = tap % 3 - 1;
#pragma unroll
        for (int k = 0; k < 4; k++) {
            int seg = tid + k * 512;      // 0..2047
            int cl  = seg >> 6;           // LDS row = output px0+cl
            int sl  = seg & 63;           // 16B slot within 512-ch row
            int px  = px0 + cl;
            int h = px / WW, w = px - (px / WW) * WW;
            bool val = (h + dy >= 0) && (h + dy < HH)
                       && (w + dx >= 0) && (w + dx < WW);
            int row = val ? (px + dy * WW + dx) : HWP;   // pad row = zeros
            R[k] = *(const short8*)(qkT + ((size_t)b * QKROW + row) * 512 + sl * 8);
        }
    };

    stage_load(0);
    int buf = 0;

    for (int tap = 0; tap < 9; tap++) {
        unsigned short* sb = &Bl[buf][0];
#pragma unroll
        for (int k = 0; k < 4; k++) {
            int seg = tid + k * 512;
            int cl = seg >> 6, sl = seg & 63;
            int slw = sl ^ (cl & 7);      // XOR bank swizzle
            *(short8*)(sb + ((size_t)cl * 64 + slw) * 8) = R[k];
        }
        __syncthreads();                  // dbuf: single barrier per tap is safe

        if (tap < 8) stage_load(tap + 1); // loads land during GEMM below

        const unsigned short* afr = w1r + (((size_t)tap * 16 * 16 + mtg) * 64 + lane) * 8;
#pragma unroll 4
        for (int ks = 0; ks < 16; ks++) {
            short8 a = *(const short8*)(afr + (size_t)ks * 16 * 512);
#pragma unroll
            for (int nt = 0; nt < 2; nt++) {
                int cl = nt * 16 + lo;
                int slot = (ks * 4 + quad) ^ (cl & 7);
                short8 bf = *(const short8*)(sb + ((size_t)cl * 64 + slot) * 8);
                acc[nt] = __builtin_amdgcn_mfma_f32_16x16x32_bf16(a, bf, acc[nt], 0, 0, 0);
            }
        }
        buf ^= 1;
    }

    // epilogue: featb[b][px][o] = bf16(acc + b1[o]);  o = mtg*16 + quad*4 + i
    const int o = mtg * 16 + quad * 4;
    const float b0 = b1[o], bb1 = b1[o + 1], bb2 = b1[o + 2], bb3 = b1[o + 3];
#pragma unroll
    for (int nt = 0; nt < 2; nt++) {
        int px = px0 + nt * 16 + lo;
        bf16x4 pk;
        pk[0] = (short)f2bf(acc[nt][0] + b0);
        pk[1] = (short)f2bf(acc[nt][1] + bb1);
        pk[2] = (short)f2bf(acc[nt][2] + bb2);
        pk[3] = (short)f2bf(acc[nt][3] + bb3);
        *(bf16x4*)(featb + ((size_t)b * QKROW + px) * 256 + o) = pk;
    }
}

// ---- conv2: tap-split(9) -> fp32 partials off9[t][b][px][32] ---------------
__global__ __launch_bounds__(256) void k_conv2(const unsigned short* __restrict__ featb,
        const unsigned short* __restrict__ w2r, float* __restrict__ off9) {
    const int tid = threadIdx.x;
    const int pb = blockIdx.x;            // 36
    const int b  = blockIdx.y;
    const int tap = blockIdx.z;
    const int lane = tid & 63, wv = tid >> 6;
    const int lo = lane & 15, quad = lane >> 4;
    const int pp = pb * 64 + wv * 16 + lo;
    const int h = pp / WW, w = pp - (pp / WW) * WW;
    const int dy = tap / 3 - 1, dx = tap % 3 - 1;
    const bool val = (h + dy >= 0) && (h + dy < HH) && (w + dx >= 0) && (w + dx < WW);
    const int row = val ? (pp + dy * WW + dx) : HWP;

    const unsigned short* brow = featb + ((size_t)b * QKROW + row) * 256 + quad * 8;
    const unsigned short* afr = w2r + (((size_t)tap * 8 * 2) * 64 + lane) * 8;

    floatx4 acc[2];
    acc[0] = (floatx4)0.f; acc[1] = (floatx4)0.f;
#pragma unroll
    for (int ks = 0; ks < 8; ks++) {
        short8 bf = *(const short8*)(brow + ks * 32);
        const unsigned short* ak = afr + (size_t)ks * 2 * 512;
        short8 a0 = *(const short8*)(ak);
        short8 a1 = *(const short8*)(ak + 512);
        acc[0] = __builtin_amdgcn_mfma_f32_16x16x32_bf16(a0, bf, acc[0], 0, 0, 0);
        acc[1] = __builtin_amdgcn_mfma_f32_16x16x32_bf16(a1, bf, acc[1], 0, 0, 0);
    }

    float* dst = off9 + (((size_t)tap * 2 + b) * HWP + pp) * 32;
#pragma unroll
    for (int mt = 0; mt < 2; mt++) {
        int o = mt * 16 + quad * 4;
        *(floatx4*)(dst + o) = acc[mt];
    }
}

// ---- osum: off[b][o][px] = sum_t off9 + b2[o]  (o<18) ----------------------
__global__ __launch_bounds__(256) void k_osum(const float* __restrict__ off9,
        const float* __restrict__ b2, float* __restrict__ off) {
    int i = blockIdx.x * 256 + threadIdx.x;        // < 2*18*2304
    int b = i / (18 * HWP);
    int r = i - b * 18 * HWP;
    int o = r / HWP, px = r - o * HWP;
    float s = b2[o];
#pragma unroll
    for (int t = 0; t < 9; t++)
        s += off9[(((size_t)t * 2 + b) * HWP + px) * 32 + o];
    off[i] = s;
}

// ---- deform: col-space tiling (round-9 structure) + qT vec4 epilogue -------
// Off loads kept per-thread (rounds 5/10 proved the off path intolerant of
// "clever" restructuring: both repack and shfl-broadcast failed correctness).
// Only change vs round 9: epilogue reads qT[px][b][c] as one floatx4 instead
// of 4 HWP-strided q scalars (epilogue 40 -> 10 lane-addrs, -6.5% of kernel).
__global__ __launch_bounds__(512, 2) void k_deform(const unsigned short* __restrict__ vT,
        const float* __restrict__ off, const unsigned short* __restrict__ wdr,
        const float* __restrict__ db, const float* __restrict__ qT,
        float* __restrict__ out) {
    __shared__ __align__(16) unsigned short Sl[2][80 * 256];   // 2 x 40 KB

    const int tid = threadIdx.x;
    const int bid = blockIdx.x;                       // 256
    const int c0 = (((bid & 7) << 5) + (bid >> 3)) * 72;
    const int lane = tid & 63, wv = tid >> 6;
    const int lo = lane & 15, quad = lane >> 4;
    const int colg = tid >> 5;                        // 0..15 staging col group
    const int slice = tid & 31;                       // 8-ch (16B) slice

    int u_pq[5];
    float u_m[5];
    const float* u_off[5];
    const unsigned short* u_vT[5];
#pragma unroll
    for (int u = 0; u < 5; u++) {
        int cl = colg + u * 16;
        int cg = min(c0 + cl, 18431);
        int pq = cg >> 3, n = cg & 7;
        u_pq[u] = pq;
        u_m[u]  = (cl < 72) ? 1.f : 0.f;
        u_off[u] = off + (size_t)(n >> 2) * 18 * HWP + pq;
        u_vT[u]  = vT + (size_t)n * HWP * 256 + slice * 8;
    }

    floatx4 acc[2][5];
#pragma unroll
    for (int mt = 0; mt < 2; mt++)
#pragma unroll
        for (int nt = 0; nt < 5; nt++) acc[mt][nt] = (floatx4)0.f;

    short8 P[5][4];
    float  cwt[5][4];
    float  ndy[5], ndx[5];

    auto prefetch_off = [&](int tap) {
#pragma unroll
        for (int u = 0; u < 5; u++) {
            ndy[u] = u_off[u][(2 * tap) * HWP];
            ndx[u] = u_off[u][(2 * tap + 1) * HWP];
        }
    };

    auto prefetch_body = [&](int tap) {
        const float kdy = (float)(tap / 3 - 1), kdx = (float)(tap % 3 - 1);
#pragma unroll
        for (int u = 0; u < 5; u++) {
            int pq = u_pq[u];
            int h = pq / WW, w = pq - (pq / WW) * WW;
            float py = ndy[u] + (float)h + kdy;
            float px = ndx[u] + (float)w + kdx;
            float y0f = floorf(py), x0f = floorf(px);
            int y0 = (int)y0f, x0 = (int)x0f;
            float fy = py - y0f, fx = px - x0f;
            bool y0ok = (y0 >= 0) & (y0 < HH), y1ok = (y0 >= -1) & (y0 < HH - 1);
            bool x0ok = (x0 >= 0) & (x0 < WW), x1ok = (x0 >= -1) & (x0 < WW - 1);
            int y0c = min(max(y0, 0), HH - 1), y1c = min(max(y0 + 1, 0), HH - 1);
            int x0c = min(max(x0, 0), WW - 1), x1c = min(max(x0 + 1, 0), WW - 1);
            const unsigned short* r0 = u_vT[u] + (size_t)(y0c * WW + x0c) * 256;
            const unsigned short* r1 = u_vT[u] + (size_t)(y0c * WW + x1c) * 256;
            const unsigned short* r2 = u_vT[u] + (size_t)(y1c * WW + x0c) * 256;
            const unsigned short* r3 = u_vT[u] + (size_t)(y1c * WW + x1c) * 256;
            float m = u_m[u];
            cwt[u][0] = (y0ok && x0ok) ? m * (1.f - fy) * (1.f - fx) : 0.f;
            cwt[u][1] = (y0ok && x1ok) ? m * (1.f - fy) * fx         : 0.f;
            cwt[u][2] = (y1ok && x0ok) ? m * fy * (1.f - fx)         : 0.f;
            cwt[u][3] = (y1ok && x1ok) ? m * fy * fx                 : 0.f;
            P[u][0] = *(const short8*)(r0);
            P[u][1] = *(const short8*)(r1);
            P[u][2] = *(const short8*)(r2);
            P[u][3] = *(const short8*)(r3);
        }
    };

    prefetch_off(0);
    prefetch_body(0);
    int buf = 0;

    for (int tap = 0; tap < 9; tap++) {
        if (tap < 8) prefetch_off(tap + 1);
        unsigned short* sb = &Sl[buf][0];
#pragma unroll
        for (int u = 0; u < 5; u++) {
            float w0 = cwt[u][0], w1 = cwt[u][1], w2 = cwt[u][2], w3 = cwt[u][3];
            short8 ov;
#pragma unroll
            for (int j = 0; j < 8; j++) {
                float s = w0 * bf2f(P[u][0][j]) + w1 * bf2f(P[u][1][j])
                        + w2 * bf2f(P[u][2][j]) + w3 * bf2f(P[u][3][j]);
                ov[j] = (short)f2bf(s);
            }
            int cl = colg + u * 16;
            int slot = slice ^ (cl & 7);
            *(short8*)(sb + cl * 256 + slot * 8) = ov;
        }
        __syncthreads();

        if (tap < 8) prefetch_body(tap + 1);

        const unsigned short* afr = wdr + (((size_t)tap * 8 * 16 + wv * 2) * 64 + lane) * 8;
#pragma unroll
        for (int ks = 0; ks < 8; ks++) {
            const unsigned short* ak = afr + (size_t)ks * 16 * 512;
            short8 a0 = *(const short8*)(ak);
            short8 a1 = *(const short8*)(ak + 512);
#pragma unroll
            for (int nt = 0; nt < 5; nt++) {
                int cl = nt * 16 + lo;
                int slot = (ks * 4 + quad) ^ (cl & 7);
                short8 bf = *(const short8*)(sb + cl * 256 + slot * 8);
                acc[0][nt] = __builtin_amdgcn_mfma_f32_16x16x32_bf16(a0, bf, acc[0][nt], 0, 0, 0);
                acc[1][nt] = __builtin_amdgcn_mfma_f32_16x16x32_bf16(a1, bf, acc[1][nt], 0, 0, 0);
            }
        }
        __syncthreads();
        buf ^= 1;
    }

#pragma unroll
    for (int mt = 0; mt < 2; mt++) {
        int o = wv * 32 + mt * 16 + quad * 4;
        float d0 = db[o], d1 = db[o + 1], d2 = db[o + 2], d3 = db[o + 3];
#pragma unroll
        for (int nt = 0; nt < 5; nt++) {
            int cl = nt * 16 + lo;
            if (cl < 72) {
                int cg = c0 + cl;
                int pq = cg >> 3, b = (cg & 7) >> 2;
                floatx4 qv = *(const floatx4*)(qT + ((size_t)pq * 2 + b) * 256 + o);
                floatx4 r = acc[mt][nt];
                r[0] += d0 + qv[0];
                r[1] += d1 + qv[1];
                r[2] += d2 + qv[2];
                r[3] += d3 + qv[3];
                *(floatx4*)(out + (size_t)cg * CC + o) = r;
            }
        }
    }
}

extern "C" void kernel_launch(void* const* d_in, const int* in_sizes, int n_in,
                              void* d_out, int out_size, void* d_ws, size_t ws_size,
                              hipStream_t stream) {
    const float* q  = (const float*)d_in[0];
    const float* k  = (const float*)d_in[1];
    const float* v  = (const float*)d_in[2];
    const float* w1 = (const float*)d_in[3];
    const float* b1 = (const float*)d_in[4];
    const float* w2 = (const float*)d_in[5];
    const float* b2 = (const float*)d_in[6];
    const float* dw = (const float*)d_in[7];
    const float* db = (const float*)d_in[8];
    float* out = (float*)d_out;

    // ws layout (~40 MB): off | qT (dead feat3 region) | off9 || qkT | vT | featb | w1r | wdr | w2r
    float* off   = (float*)d_ws;                          //    82,944 f
    float* qT    = off + 82944;                           // 1,179,648 f used (of 3,538,944)
    float* off9  = qT + 3538944;                          // 1,327,104 f
    unsigned short* qkT   = (unsigned short*)(off9 + 1327104);
    unsigned short* vT    = qkT + 2360320;                // 2*2305*512
    unsigned short* featb = vT + 4718592;                 // 2*2305*256
    unsigned short* w1r   = featb + 1180160;              // frag order
    unsigned short* wdr   = w1r + 1179648;
    unsigned short* w2r   = wdr + 589824;

    hipLaunchKernelGGL(k_tr,    dim3(36, 4, 12), dim3(256), 0, stream, q, k, v, qkT, qT, vT);
    hipLaunchKernelGGL(k_prep_w,dim3(7201),      dim3(256), 0, stream, w1, dw, w2, w1r, wdr, w2r, qkT, featb);
    hipLaunchKernelGGL(k_conv1, dim3(72, 2, 2),  dim3(512), 0, stream, qkT, w1r, b1, featb);
    hipLaunchKernelGGL(k_conv2, dim3(36, 2, 9),  dim3(256), 0, stream, featb, w2r, off9);
    hipLaunchKernelGGL(k_osum,  dim3(324),       dim3(256), 0, stream, off9, b2, off);
    hipLaunchKernelGGL(k_deform,dim3(256),       dim3(512), 0, stream, vT, off, wdr, db, qT, out);
}

// Round 13
// 205.054 us; speedup vs baseline: 1.2260x; 1.0109x over previous
//
#include <hip/hip_runtime.h>

// Problem constants: B=2, obj=4, C=256, H=W=48, N=8, HW=2304
#define HH 48
#define WW 48
#define HWP 2304
#define CC 256
#define NB 8
#define QKROW 2305   // 2304 rows + 1 zero pad row (index 2304) for OOB taps

typedef __attribute__((ext_vector_type(8))) short short8;   // 8 x bf16 = 4 VGPR
typedef __attribute__((ext_vector_type(4))) short bf16x4;   // 4 x bf16 = 8B
typedef __attribute__((ext_vector_type(4))) float floatx4;  // MFMA C/D frag

static __device__ __forceinline__ unsigned short f2bf(float f) {
    union { float f; unsigned u; } v; v.f = f;
    unsigned r = v.u + 0x7fffu + ((v.u >> 16) & 1u);        // RNE
    return (unsigned short)(r >> 16);
}
static __device__ __forceinline__ float bf2f(short v) {
    union { unsigned u; float f; } x; x.u = ((unsigned)(unsigned short)v) << 16;
    return x.f;
}

// ---- merged: bid<7201 -> weight preshuffle (+pad zero); else transposes ----
// prep:  w1r [tap][kk16][mtg16][l][j], wdr [tap][kk8][mtg16][l][j],
//        w2r [tap][kk8][mt2][l][j] (o>=18 zero); block 7200 zeroes pad rows.
// tr:    z<4 -> q/k -> qkT[b][px][c2] (+qT[px][b][c] f32); z>=4 -> v -> vT.
__global__ __launch_bounds__(256) void k_trprep(const float* __restrict__ q,
        const float* __restrict__ kk, const float* __restrict__ v,
        const float* __restrict__ w1, const float* __restrict__ dw,
        const float* __restrict__ w2, unsigned short* __restrict__ qkT,
        float* __restrict__ qT, unsigned short* __restrict__ vT,
        unsigned short* __restrict__ w1r, unsigned short* __restrict__ wdr,
        unsigned short* __restrict__ w2r, unsigned short* __restrict__ featb) {
    __shared__ float T[64][65];
    const int bid = blockIdx.x;
    if (bid < 7201) {
        if (bid == 7200) {
            int t = threadIdx.x;
#pragma unroll
            for (int b = 0; b < 2; b++) {
                qkT[((size_t)b * QKROW + HWP) * 512 + t] = 0;
                qkT[((size_t)b * QKROW + HWP) * 512 + 256 + t] = 0;
                featb[((size_t)b * QKROW + HWP) * 256 + t] = 0;
            }
            return;
        }
        int idx = bid * 256 + threadIdx.x;
        if (idx < 1179648) {
            int j = idx & 7, l = (idx >> 3) & 63, mtg = (idx >> 9) & 15;
            int kkk = (idx >> 13) & 15, tap = idx >> 17;
            int o = mtg * 16 + (l & 15);
            int c2 = kkk * 32 + (l >> 4) * 8 + j;
            w1r[idx] = f2bf(w1[((size_t)o * 512 + c2) * 9 + tap]);
        } else if (idx < 1179648 + 589824) {
            int i2 = idx - 1179648;
            int j = i2 & 7, l = (i2 >> 3) & 63, mtg = (i2 >> 9) & 15;
            int kkk = (i2 >> 13) & 7, tap = i2 >> 16;
            int o = mtg * 16 + (l & 15);
            int c = kkk * 32 + (l >> 4) * 8 + j;
            wdr[i2] = f2bf(dw[((size_t)o * 256 + c) * 9 + tap]);
        } else {
            int i2 = idx - 1179648 - 589824;
            int j = i2 & 7, l = (i2 >> 3) & 63, mt = (i2 >> 9) & 1;
            int kkk = (i2 >> 10) & 7, tap = i2 >> 13;
            int o = mt * 16 + (l & 15);
            int c = kkk * 32 + (l >> 4) * 8 + j;
            w2r[i2] = (o < 18) ? f2bf(w2[((size_t)o * 256 + c) * 9 + tap]) : 0;
        }
        return;
    }
    const int idx2 = bid - 7201;           // 0..1727
    const int pg = idx2 % 36;
    const int rest = idx2 / 36;
    const int cg = rest & 3, z = rest >> 2;   // cg 0..3, z 0..11
    const int tx = threadIdx.x & 63, ty = threadIdx.x >> 6;
    if (z < 4) {
        const int b = z >> 1, src = z & 1;
        const float* s = (src ? kk : q) + (size_t)b * CC * HWP;
#pragma unroll
        for (int i = 0; i < 16; i++) {
            int cl = ty * 16 + i;
            T[cl][tx] = s[(size_t)(cg * 64 + cl) * HWP + pg * 64 + tx];
        }
        __syncthreads();
#pragma unroll
        for (int i = 0; i < 16; i++) {
            int pxl = ty * 16 + i;
            float val = T[tx][pxl];
            qkT[((size_t)b * QKROW + pg * 64 + pxl) * 512 + src * 256 + cg * 64 + tx]
                = f2bf(val);
            if (src == 0)
                qT[((size_t)(pg * 64 + pxl) * 2 + b) * 256 + cg * 64 + tx] = val;
        }
    } else {
        const int n = z - 4;
        const float* s = v + (size_t)n * CC * HWP;
#pragma unroll
        for (int i = 0; i < 16; i++) {
            int cl = ty * 16 + i;
            T[cl][tx] = s[(size_t)(cg * 64 + cl) * HWP + pg * 64 + tx];
        }
        __syncthreads();
#pragma unroll
        for (int i = 0; i < 16; i++) {
            int pxl = ty * 16 + i;
            vT[((size_t)n * HWP + pg * 64 + pxl) * 256 + cg * 64 + tx] = f2bf(T[tx][pxl]);
        }
    }
}

// ---- conv1 v3: k_deform-structure port (verified round 9, ~30us) -----------
__global__ __launch_bounds__(512, 4) void k_conv1(const unsigned short* __restrict__ qkT,
        const unsigned short* __restrict__ w1r, const float* __restrict__ b1,
        unsigned short* __restrict__ featb) {
    __shared__ __align__(16) unsigned short Bl[2][32 * 64 * 8];   // 2 x 32 KB

    const int tid = threadIdx.x;          // 0..511
    const int pt = blockIdx.x;            // 72 px-tiles of 32
    const int b  = blockIdx.y;
    const int oh = blockIdx.z;            // out half (128 outs)
    const int px0 = pt * 32;
    const int lane = tid & 63, wv = tid >> 6;   // 8 waves
    const int lo = lane & 15, quad = lane >> 4;
    const int mtg = oh * 8 + wv;          // this wave's 16-out group

    floatx4 acc[2];
    acc[0] = (floatx4)0.f; acc[1] = (floatx4)0.f;

    short8 R[4];                          // prefetched staging rows (next tap)
    auto stage_load = [&](int tap) {
        const int dy = tap / 3 - 1, dx = tap % 3 - 1;
#pragma unroll
        for (int k = 0; k < 4; k++) {
            int seg = tid + k * 512;      // 0..2047
            int cl  = seg >> 6;           // LDS row = output px0+cl
            int sl  = seg & 63;           // 16B slot within 512-ch row
            int px  = px0 + cl;
            int h = px / WW, w = px - (px / WW) * WW;
            bool val = (h + dy >= 0) && (h + dy < HH)
                       && (w + dx >= 0) && (w + dx < WW);
            int row = val ? (px + dy * WW + dx) : HWP;   // pad row = zeros
            R[k] = *(const short8*)(qkT + ((size_t)b * QKROW + row) * 512 + sl * 8);
        }
    };

    stage_load(0);
    int buf = 0;

    for (int tap = 0; tap < 9; tap++) {
        unsigned short* sb = &Bl[buf][0];
#pragma unroll
        for (int k = 0; k < 4; k++) {
            int seg = tid + k * 512;
            int cl = seg >> 6, sl = seg & 63;
            int slw = sl ^ (cl & 7);      // XOR bank swizzle
            *(short8*)(sb + ((size_t)cl * 64 + slw) * 8) = R[k];
        }
        __syncthreads();                  // dbuf: single barrier per tap is safe

        if (tap < 8) stage_load(tap + 1); // loads land during GEMM below

        const unsigned short* afr = w1r + (((size_t)tap * 16 * 16 + mtg) * 64 + lane) * 8;
#pragma unroll 4
        for (int ks = 0; ks < 16; ks++) {
            short8 a = *(const short8*)(afr + (size_t)ks * 16 * 512);
#pragma unroll
            for (int nt = 0; nt < 2; nt++) {
                int cl = nt * 16 + lo;
                int slot = (ks * 4 + quad) ^ (cl & 7);
                short8 bf = *(const short8*)(sb + ((size_t)cl * 64 + slot) * 8);
                acc[nt] = __builtin_amdgcn_mfma_f32_16x16x32_bf16(a, bf, acc[nt], 0, 0, 0);
            }
        }
        buf ^= 1;
    }

    // epilogue: featb[b][px][o] = bf16(acc + b1[o]);  o = mtg*16 + quad*4 + i
    const int o = mtg * 16 + quad * 4;
    const float b0 = b1[o], bb1 = b1[o + 1], bb2 = b1[o + 2], bb3 = b1[o + 3];
#pragma unroll
    for (int nt = 0; nt < 2; nt++) {
        int px = px0 + nt * 16 + lo;
        bf16x4 pk;
        pk[0] = (short)f2bf(acc[nt][0] + b0);
        pk[1] = (short)f2bf(acc[nt][1] + bb1);
        pk[2] = (short)f2bf(acc[nt][2] + bb2);
        pk[3] = (short)f2bf(acc[nt][3] + bb3);
        *(bf16x4*)(featb + ((size_t)b * QKROW + px) * 256 + o) = pk;
    }
}

// ---- conv2 v2: all 9 taps per block (conv1-v3 skeleton), osum fused --------
// Old: 648 tap-split blocks -> off9 partials (10.6MB R+W) + k_osum dispatch.
// v2: 72 blocks = 36 px-tiles(64) x 2 b; 8 waves = 2 mtg x 4 px-blocks.
// Per tap: reg-prefetched staging (R[4]) -> LDS dbuf (2x32KB), single barrier,
// GEMM accumulates across taps. Epilogue adds b2 and writes off directly.
__global__ __launch_bounds__(512, 2) void k_conv2(const unsigned short* __restrict__ featb,
        const unsigned short* __restrict__ w2r, const float* __restrict__ b2,
        float* __restrict__ off) {
    __shared__ __align__(16) unsigned short Bl[2][64 * 32 * 8];   // 2 x 32 KB

    const int tid = threadIdx.x;          // 0..511
    const int pt = blockIdx.x;            // 36 px-tiles of 64
    const int b  = blockIdx.y;
    const int px0 = pt * 64;
    const int lane = tid & 63, wv = tid >> 6;   // 8 waves
    const int lo = lane & 15, quad = lane >> 4;
    const int mtg = wv & 1;               // 16-out group (only o<18 stored)
    const int pxb = wv >> 1;              // 16-px block within the 64

    floatx4 acc = (floatx4)0.f;

    short8 R[4];
    auto stage_load = [&](int tap) {
        const int dy = tap / 3 - 1, dx = tap % 3 - 1;
#pragma unroll
        for (int k = 0; k < 4; k++) {
            int seg = tid + k * 512;      // 0..2047 = cl*32 + sl
            int cl  = seg >> 5;           // 64 rows
            int sl  = seg & 31;           // 16B slot within 256-ch row
            int px  = px0 + cl;
            int h = px / WW, w = px - (px / WW) * WW;
            bool val = (h + dy >= 0) && (h + dy < HH)
                       && (w + dx >= 0) && (w + dx < WW);
            int row = val ? (px + dy * WW + dx) : HWP;   // pad row = zeros
            R[k] = *(const short8*)(featb + ((size_t)b * QKROW + row) * 256 + sl * 8);
        }
    };

    stage_load(0);
    int buf = 0;

    for (int tap = 0; tap < 9; tap++) {
        unsigned short* sb = &Bl[buf][0];
#pragma unroll
        for (int k = 0; k < 4; k++) {
            int seg = tid + k * 512;
            int cl = seg >> 5, sl = seg & 31;
            int slw = sl ^ (cl & 7);      // XOR bank swizzle
            *(short8*)(sb + ((size_t)cl * 32 + slw) * 8) = R[k];
        }
        __syncthreads();                  // dbuf: single barrier per tap (conv1-v3 proof)

        if (tap < 8) stage_load(tap + 1);

        // A-frag: w2r index = ((tap*8 + ks)*2 + mtg)*512 + lane*8
#pragma unroll
        for (int ks = 0; ks < 8; ks++) {
            short8 a = *(const short8*)(w2r + ((((size_t)tap * 8 + ks) * 2 + mtg) * 64 + lane) * 8);
            int cl = pxb * 16 + lo;
            int slot = (ks * 4 + quad) ^ (cl & 7);
            short8 bf = *(const short8*)(sb + ((size_t)cl * 32 + slot) * 8);
            acc = __builtin_amdgcn_mfma_f32_16x16x32_bf16(a, bf, acc, 0, 0, 0);
        }
        buf ^= 1;
    }

    // epilogue: off[b][oc][px] = acc + b2[oc], oc < 18 only
    const int o = mtg * 16 + quad * 4;
    const int px = px0 + pxb * 16 + lo;
#pragma unroll
    for (int i = 0; i < 4; i++) {
        int oc = o + i;
        if (oc < 18)
            off[((size_t)b * 18 + oc) * HWP + px] = acc[i] + b2[oc];
    }
}

// ---- deform: col-space tiling (round-11 exact: passing, 66.6us) ------------
// Off loads per-thread: three restructuring attempts (repack r5, shfl r10,
// LDS broadcast r12) all failed correctness -> path frozen.
__global__ __launch_bounds__(512, 2) void k_deform(const unsigned short* __restrict__ vT,
        const float* __restrict__ off, const unsigned short* __restrict__ wdr,
        const float* __restrict__ db, const float* __restrict__ qT,
        float* __restrict__ out) {
    __shared__ __align__(16) unsigned short Sl[2][80 * 256];   // 2 x 40 KB

    const int tid = threadIdx.x;
    const int bid = blockIdx.x;                       // 256
    const int c0 = (((bid & 7) << 5) + (bid >> 3)) * 72;
    const int lane = tid & 63, wv = tid >> 6;
    const int lo = lane & 15, quad = lane >> 4;
    const int colg = tid >> 5;                        // 0..15 staging col group
    const int slice = tid & 31;                       // 8-ch (16B) slice

    int u_pq[5];
    float u_m[5];
    const float* u_off[5];
    const unsigned short* u_vT[5];
#pragma unroll
    for (int u = 0; u < 5; u++) {
        int cl = colg + u * 16;
        int cg = min(c0 + cl, 18431);
        int pq = cg >> 3, n = cg & 7;
        u_pq[u] = pq;
        u_m[u]  = (cl < 72) ? 1.f : 0.f;
        u_off[u] = off + (size_t)(n >> 2) * 18 * HWP + pq;
        u_vT[u]  = vT + (size_t)n * HWP * 256 + slice * 8;
    }

    floatx4 acc[2][5];
#pragma unroll
    for (int mt = 0; mt < 2; mt++)
#pragma unroll
        for (int nt = 0; nt < 5; nt++) acc[mt][nt] = (floatx4)0.f;

    short8 P[5][4];
    float  cwt[5][4];
    float  ndy[5], ndx[5];

    auto prefetch_off = [&](int tap) {
#pragma unroll
        for (int u = 0; u < 5; u++) {
            ndy[u] = u_off[u][(2 * tap) * HWP];
            ndx[u] = u_off[u][(2 * tap + 1) * HWP];
        }
    };

    auto prefetch_body = [&](int tap) {
        const float kdy = (float)(tap / 3 - 1), kdx = (float)(tap % 3 - 1);
#pragma unroll
        for (int u = 0; u < 5; u++) {
            int pq = u_pq[u];
            int h = pq / WW, w = pq - (pq / WW) * WW;
            float py = ndy[u] + (float)h + kdy;
            float px = ndx[u] + (float)w + kdx;
            float y0f = floorf(py), x0f = floorf(px);
            int y0 = (int)y0f, x0 = (int)x0f;
            float fy = py - y0f, fx = px - x0f;
            bool y0ok = (y0 >= 0) & (y0 < HH), y1ok = (y0 >= -1) & (y0 < HH - 1);
            bool x0ok = (x0 >= 0) & (x0 < WW), x1ok = (x0 >= -1) & (x0 < WW - 1);
            int y0c = min(max(y0, 0), HH - 1), y1c = min(max(y0 + 1, 0), HH - 1);
            int x0c = min(max(x0, 0), WW - 1), x1c = min(max(x0 + 1, 0), WW - 1);
            const unsigned short* r0 = u_vT[u] + (size_t)(y0c * WW + x0c) * 256;
            const unsigned short* r1 = u_vT[u] + (size_t)(y0c * WW + x1c) * 256;
            const unsigned short* r2 = u_vT[u] + (size_t)(y1c * WW + x0c) * 256;
            const unsigned short* r3 = u_vT[u] + (size_t)(y1c * WW + x1c) * 256;
            float m = u_m[u];
            cwt[u][0] = (y0ok && x0ok) ? m * (1.f - fy) * (1.f - fx) : 0.f;
            cwt[u][1] = (y0ok && x1ok) ? m * (1.f - fy) * fx         : 0.f;
            cwt[u][2] = (y1ok && x0ok) ? m * fy * (1.f - fx)         : 0.f;
            cwt[u][3] = (y1ok && x1ok) ? m * fy * fx                 : 0.f;
            P[u][0] = *(const short8*)(r0);
            P[u][1] = *(const short8*)(r1);
            P[u][2] = *(const short8*)(r2);
            P[u][3] = *(const short8*)(r3);
        }
    };

    prefetch_off(0);
    prefetch_body(0);
    int buf = 0;

    for (int tap = 0; tap < 9; tap++) {
        if (tap < 8) prefetch_off(tap + 1);
        unsigned short* sb = &Sl[buf][0];
#pragma unroll
        for (int u = 0; u < 5; u++) {
            float w0 = cwt[u][0], w1 = cwt[u][1], w2 = cwt[u][2], w3 = cwt[u][3];
            short8 ov;
#pragma unroll
            for (int j = 0; j < 8; j++) {
                float s = w0 * bf2f(P[u][0][j]) + w1 * bf2f(P[u][1][j])
                        + w2 * bf2f(P[u][2][j]) + w3 * bf2f(P[u][3][j]);
                ov[j] = (short)f2bf(s);
            }
            int cl = colg + u * 16;
            int slot = slice ^ (cl & 7);
            *(short8*)(sb + cl * 256 + slot * 8) = ov;
        }
        __syncthreads();

        if (tap < 8) prefetch_body(tap + 1);

        const unsigned short* afr = wdr + (((size_t)tap * 8 * 16 + wv * 2) * 64 + lane) * 8;
#pragma unroll
        for (int ks = 0; ks < 8; ks++) {
            const unsigned short* ak = afr + (size_t)ks * 16 * 512;
            short8 a0 = *(const short8*)(ak);
            short8 a1 = *(const short8*)(ak + 512);
#pragma unroll
            for (int nt = 0; nt < 5; nt++) {
                int cl = nt * 16 + lo;
                int slot = (ks * 4 + quad) ^ (cl & 7);
                short8 bf = *(const short8*)(sb + cl * 256 + slot * 8);
                acc[0][nt] = __builtin_amdgcn_mfma_f32_16x16x32_bf16(a0, bf, acc[0][nt], 0, 0, 0);
                acc[1][nt] = __builtin_amdgcn_mfma_f32_16x16x32_bf16(a1, bf, acc[1][nt], 0, 0, 0);
            }
        }
        __syncthreads();
        buf ^= 1;
    }

#pragma unroll
    for (int mt = 0; mt < 2; mt++) {
        int o = wv * 32 + mt * 16 + quad * 4;
        float d0 = db[o], d1 = db[o + 1], d2 = db[o + 2], d3 = db[o + 3];
#pragma unroll
        for (int nt = 0; nt < 5; nt++) {
            int cl = nt * 16 + lo;
            if (cl < 72) {
                int cg = c0 + cl;
                int pq = cg >> 3, b = (cg & 7) >> 2;
                floatx4 qv = *(const floatx4*)(qT + ((size_t)pq * 2 + b) * 256 + o);
                floatx4 r = acc[mt][nt];
                r[0] += d0 + qv[0];
                r[1] += d1 + qv[1];
                r[2] += d2 + qv[2];
                r[3] += d3 + qv[3];
                *(floatx4*)(out + (size_t)cg * CC + o) = r;
            }
        }
    }
}

extern "C" void kernel_launch(void* const* d_in, const int* in_sizes, int n_in,
                              void* d_out, int out_size, void* d_ws, size_t ws_size,
                              hipStream_t stream) {
    const float* q  = (const float*)d_in[0];
    const float* k  = (const float*)d_in[1];
    const float* v  = (const float*)d_in[2];
    const float* w1 = (const float*)d_in[3];
    const float* b1 = (const float*)d_in[4];
    const float* w2 = (const float*)d_in[5];
    const float* b2 = (const float*)d_in[6];
    const float* dw = (const float*)d_in[7];
    const float* db = (const float*)d_in[8];
    float* out = (float*)d_out;

    // ws layout (~40 MB): off | qT (dead feat3 region) | (off9 dead) || qkT | vT | featb | w1r | wdr | w2r
    float* off   = (float*)d_ws;                          //    82,944 f
    float* qT    = off + 82944;                           // 1,179,648 f used
    float* off9  = qT + 3538944;                          // dead (kept for layout)
    unsigned short* qkT   = (unsigned short*)(off9 + 1327104);
    unsigned short* vT    = qkT + 2360320;                // 2*2305*512
    unsigned short* featb = vT + 4718592;                 // 2*2305*256
    unsigned short* w1r   = featb + 1180160;              // frag order
    unsigned short* wdr   = w1r + 1179648;
    unsigned short* w2r   = wdr + 589824;

    hipLaunchKernelGGL(k_trprep,dim3(8929),      dim3(256), 0, stream,
                       q, k, v, w1, dw, w2, qkT, qT, vT, w1r, wdr, w2r, featb);
    hipLaunchKernelGGL(k_conv1, dim3(72, 2, 2),  dim3(512), 0, stream, qkT, w1r, b1, featb);
    hipLaunchKernelGGL(k_conv2, dim3(36, 2),     dim3(512), 0, stream, featb, w2r, b2, off);
    hipLaunchKernelGGL(k_deform,dim3(256),       dim3(512), 0, stream, vT, off, wdr, db, qT, out);
}

// Round 15
// 199.819 us; speedup vs baseline: 1.2581x; 1.0262x over previous
//
#include <hip/hip_runtime.h>

// Problem constants: B=2, obj=4, C=256, H=W=48, N=8, HW=2304
#define HH 48
#define WW 48
#define HWP 2304
#define CC 256
#define NB 8
#define QKROW 2305   // 2304 rows + 1 zero pad row (index 2304) for OOB taps

typedef __attribute__((ext_vector_type(8))) short short8;   // 8 x bf16 = 4 VGPR
typedef __attribute__((ext_vector_type(4))) short bf16x4;   // 4 x bf16 = 8B
typedef __attribute__((ext_vector_type(4))) float floatx4;  // MFMA C/D frag

static __device__ __forceinline__ unsigned short f2bf(float f) {
    union { float f; unsigned u; } v; v.f = f;
    unsigned r = v.u + 0x7fffu + ((v.u >> 16) & 1u);        // RNE
    return (unsigned short)(r >> 16);
}
static __device__ __forceinline__ float bf2f(short v) {
    union { unsigned u; float f; } x; x.u = ((unsigned)(unsigned short)v) << 16;
    return x.f;
}

// ---- merged: bid<7201 -> weight preshuffle (+pad zero); else transposes ----
__global__ __launch_bounds__(256) void k_trprep(const float* __restrict__ q,
        const float* __restrict__ kk, const float* __restrict__ v,
        const float* __restrict__ w1, const float* __restrict__ dw,
        const float* __restrict__ w2, unsigned short* __restrict__ qkT,
        float* __restrict__ qT, unsigned short* __restrict__ vT,
        unsigned short* __restrict__ w1r, unsigned short* __restrict__ wdr,
        unsigned short* __restrict__ w2r, unsigned short* __restrict__ featb) {
    __shared__ float T[64][65];
    const int bid = blockIdx.x;
    if (bid < 7201) {
        if (bid == 7200) {
            int t = threadIdx.x;
#pragma unroll
            for (int b = 0; b < 2; b++) {
                qkT[((size_t)b * QKROW + HWP) * 512 + t] = 0;
                qkT[((size_t)b * QKROW + HWP) * 512 + 256 + t] = 0;
                featb[((size_t)b * QKROW + HWP) * 256 + t] = 0;
            }
            return;
        }
        int idx = bid * 256 + threadIdx.x;
        if (idx < 1179648) {
            int j = idx & 7, l = (idx >> 3) & 63, mtg = (idx >> 9) & 15;
            int kkk = (idx >> 13) & 15, tap = idx >> 17;
            int o = mtg * 16 + (l & 15);
            int c2 = kkk * 32 + (l >> 4) * 8 + j;
            w1r[idx] = f2bf(w1[((size_t)o * 512 + c2) * 9 + tap]);
        } else if (idx < 1179648 + 589824) {
            int i2 = idx - 1179648;
            int j = i2 & 7, l = (i2 >> 3) & 63, mtg = (i2 >> 9) & 15;
            int kkk = (i2 >> 13) & 7, tap = i2 >> 16;
            int o = mtg * 16 + (l & 15);
            int c = kkk * 32 + (l >> 4) * 8 + j;
            wdr[i2] = f2bf(dw[((size_t)o * 256 + c) * 9 + tap]);
        } else {
            int i2 = idx - 1179648 - 589824;
            int j = i2 & 7, l = (i2 >> 3) & 63, mt = (i2 >> 9) & 1;
            int kkk = (i2 >> 10) & 7, tap = i2 >> 13;
            int o = mt * 16 + (l & 15);
            int c = kkk * 32 + (l >> 4) * 8 + j;
            w2r[i2] = (o < 18) ? f2bf(w2[((size_t)o * 256 + c) * 9 + tap]) : 0;
        }
        return;
    }
    const int idx2 = bid - 7201;           // 0..1727
    const int pg = idx2 % 36;
    const int rest = idx2 / 36;
    const int cg = rest & 3, z = rest >> 2;   // cg 0..3, z 0..11
    const int tx = threadIdx.x & 63, ty = threadIdx.x >> 6;
    if (z < 4) {
        const int b = z >> 1, src = z & 1;
        const float* s = (src ? kk : q) + (size_t)b * CC * HWP;
#pragma unroll
        for (int i = 0; i < 16; i++) {
            int cl = ty * 16 + i;
            T[cl][tx] = s[(size_t)(cg * 64 + cl) * HWP + pg * 64 + tx];
        }
        __syncthreads();
#pragma unroll
        for (int i = 0; i < 16; i++) {
            int pxl = ty * 16 + i;
            float val = T[tx][pxl];
            qkT[((size_t)b * QKROW + pg * 64 + pxl) * 512 + src * 256 + cg * 64 + tx]
                = f2bf(val);
            if (src == 0)
                qT[((size_t)(pg * 64 + pxl) * 2 + b) * 256 + cg * 64 + tx] = val;
        }
    } else {
        const int n = z - 4;
        const float* s = v + (size_t)n * CC * HWP;
#pragma unroll
        for (int i = 0; i < 16; i++) {
            int cl = ty * 16 + i;
            T[cl][tx] = s[(size_t)(cg * 64 + cl) * HWP + pg * 64 + tx];
        }
        __syncthreads();
#pragma unroll
        for (int i = 0; i < 16; i++) {
            int pxl = ty * 16 + i;
            vT[((size_t)n * HWP + pg * 64 + pxl) * 256 + cg * 64 + tx] = f2bf(T[tx][pxl]);
        }
    }
}

// ---- conv1 v3: k_deform-structure port (verified round 9, ~30us) -----------
__global__ __launch_bounds__(512, 4) void k_conv1(const unsigned short* __restrict__ qkT,
        const unsigned short* __restrict__ w1r, const float* __restrict__ b1,
        unsigned short* __restrict__ featb) {
    __shared__ __align__(16) unsigned short Bl[2][32 * 64 * 8];   // 2 x 32 KB

    const int tid = threadIdx.x;          // 0..511
    const int pt = blockIdx.x;            // 72 px-tiles of 32
    const int b  = blockIdx.y;
    const int oh = blockIdx.z;            // out half (128 outs)
    const int px0 = pt * 32;
    const int lane = tid & 63, wv = tid >> 6;   // 8 waves
    const int lo = lane & 15, quad = lane >> 4;
    const int mtg = oh * 8 + wv;          // this wave's 16-out group

    floatx4 acc[2];
    acc[0] = (floatx4)0.f; acc[1] = (floatx4)0.f;

    short8 R[4];                          // prefetched staging rows (next tap)
    auto stage_load = [&](int tap) {
        const int dy = tap / 3 - 1, dx = tap % 3 - 1;
#pragma unroll
        for (int k = 0; k < 4; k++) {
            int seg = tid + k * 512;      // 0..2047
            int cl  = seg >> 6;           // LDS row = output px0+cl
            int sl  = seg & 63;           // 16B slot within 512-ch row
            int px  = px0 + cl;
            int h = px / WW, w = px - (px / WW) * WW;
            bool val = (h + dy >= 0) && (h + dy < HH)
                       && (w + dx >= 0) && (w + dx < WW);
            int row = val ? (px + dy * WW + dx) : HWP;   // pad row = zeros
            R[k] = *(const short8*)(qkT + ((size_t)b * QKROW + row) * 512 + sl * 8);
        }
    };

    stage_load(0);
    int buf = 0;

    for (int tap = 0; tap < 9; tap++) {
        unsigned short* sb = &Bl[buf][0];
#pragma unroll
        for (int k = 0; k < 4; k++) {
            int seg = tid + k * 512;
            int cl = seg >> 6, sl = seg & 63;
            int slw = sl ^ (cl & 7);      // XOR bank swizzle
            *(short8*)(sb + ((size_t)cl * 64 + slw) * 8) = R[k];
        }
        __syncthreads();                  // dbuf: single barrier per tap is safe

        if (tap < 8) stage_load(tap + 1); // loads land during GEMM below

        const unsigned short* afr = w1r + (((size_t)tap * 16 * 16 + mtg) * 64 + lane) * 8;
#pragma unroll 4
        for (int ks = 0; ks < 16; ks++) {
            short8 a = *(const short8*)(afr + (size_t)ks * 16 * 512);
#pragma unroll
            for (int nt = 0; nt < 2; nt++) {
                int cl = nt * 16 + lo;
                int slot = (ks * 4 + quad) ^ (cl & 7);
                short8 bf = *(const short8*)(sb + ((size_t)cl * 64 + slot) * 8);
                acc[nt] = __builtin_amdgcn_mfma_f32_16x16x32_bf16(a, bf, acc[nt], 0, 0, 0);
            }
        }
        buf ^= 1;
    }

    // epilogue: featb[b][px][o] = bf16(acc + b1[o]);  o = mtg*16 + quad*4 + i
    const int o = mtg * 16 + quad * 4;
    const float b0 = b1[o], bb1 = b1[o + 1], bb2 = b1[o + 2], bb3 = b1[o + 3];
#pragma unroll
    for (int nt = 0; nt < 2; nt++) {
        int px = px0 + nt * 16 + lo;
        bf16x4 pk;
        pk[0] = (short)f2bf(acc[nt][0] + b0);
        pk[1] = (short)f2bf(acc[nt][1] + bb1);
        pk[2] = (short)f2bf(acc[nt][2] + bb2);
        pk[3] = (short)f2bf(acc[nt][3] + bb3);
        *(bf16x4*)(featb + ((size_t)b * QKROW + px) * 256 + o) = pk;
    }
}

// ---- conv2 v2: all 9 taps per block (conv1-v3 skeleton), osum fused --------
__global__ __launch_bounds__(512, 2) void k_conv2(const unsigned short* __restrict__ featb,
        const unsigned short* __restrict__ w2r, const float* __restrict__ b2,
        float* __restrict__ off) {
    __shared__ __align__(16) unsigned short Bl[2][64 * 32 * 8];   // 2 x 32 KB

    const int tid = threadIdx.x;          // 0..511
    const int pt = blockIdx.x;            // 36 px-tiles of 64
    const int b  = blockIdx.y;
    const int px0 = pt * 64;
    const int lane = tid & 63, wv = tid >> 6;   // 8 waves
    const int lo = lane & 15, quad = lane >> 4;
    const int mtg = wv & 1;               // 16-out group (only o<18 stored)
    const int pxb = wv >> 1;              // 16-px block within the 64

    floatx4 acc = (floatx4)0.f;

    short8 R[4];
    auto stage_load = [&](int tap) {
        const int dy = tap / 3 - 1, dx = tap % 3 - 1;
#pragma unroll
        for (int k = 0; k < 4; k++) {
            int seg = tid + k * 512;      // 0..2047 = cl*32 + sl
            int cl  = seg >> 5;           // 64 rows
            int sl  = seg & 31;           // 16B slot within 256-ch row
            int px  = px0 + cl;
            int h = px / WW, w = px - (px / WW) * WW;
            bool val = (h + dy >= 0) && (h + dy < HH)
                       && (w + dx >= 0) && (w + dx < WW);
            int row = val ? (px + dy * WW + dx) : HWP;   // pad row = zeros
            R[k] = *(const short8*)(featb + ((size_t)b * QKROW + row) * 256 + sl * 8);
        }
    };

    stage_load(0);
    int buf = 0;

    for (int tap = 0; tap < 9; tap++) {
        unsigned short* sb = &Bl[buf][0];
#pragma unroll
        for (int k = 0; k < 4; k++) {
            int seg = tid + k * 512;
            int cl = seg >> 5, sl = seg & 31;
            int slw = sl ^ (cl & 7);      // XOR bank swizzle
            *(short8*)(sb + ((size_t)cl * 32 + slw) * 8) = R[k];
        }
        __syncthreads();                  // dbuf: single barrier per tap (conv1-v3 proof)

        if (tap < 8) stage_load(tap + 1);

#pragma unroll
        for (int ks = 0; ks < 8; ks++) {
            short8 a = *(const short8*)(w2r + ((((size_t)tap * 8 + ks) * 2 + mtg) * 64 + lane) * 8);
            int cl = pxb * 16 + lo;
            int slot = (ks * 4 + quad) ^ (cl & 7);
            short8 bf = *(const short8*)(sb + ((size_t)cl * 32 + slot) * 8);
            acc = __builtin_amdgcn_mfma_f32_16x16x32_bf16(a, bf, acc, 0, 0, 0);
        }
        buf ^= 1;
    }

    // epilogue: off[b][oc][px] = acc + b2[oc], oc < 18 only
    const int o = mtg * 16 + quad * 4;
    const int px = px0 + pxb * 16 + lo;
#pragma unroll
    for (int i = 0; i < 4; i++) {
        int oc = o + i;
        if (oc < 18)
            off[((size_t)b * 18 + oc) * HWP + px] = acc[i] + b2[oc];
    }
}

// ---- deform: col-space tiling, 72-row LDS (2 blocks/CU), phantom skip ------
// Change vs round 11/13 (ONLY this, isolated): Sl 80->72 rows = 2x36KB; the
// 8 phantom rows (staging cols 72-79, unit 4 of colg>=8, wave-uniform) were
// zeros feeding MFMA columns the epilogue discards -> skip their off-loads,
// gathers, interp, LDS writes entirely; GEMM B-reads clamp row to 71 (those
// acc columns are garbage and discarded by the existing cl<72 guard).
// 2x72KB = 144KB <= 160KB -> 2 blocks/CU (was 1 at 2x80KB): occupancy ~2x.
// Off loads stay per-thread (frozen: r5/r10/r12 restructures all failed).
__global__ __launch_bounds__(512, 2) void k_deform(const unsigned short* __restrict__ vT,
        const float* __restrict__ off, const unsigned short* __restrict__ wdr,
        const float* __restrict__ db, const float* __restrict__ qT,
        float* __restrict__ out) {
    __shared__ __align__(16) unsigned short Sl[2][72 * 256];   // 2 x 36 KB

    const int tid = threadIdx.x;
    const int bid = blockIdx.x;                       // 256
    const int c0 = (((bid & 7) << 5) + (bid >> 3)) * 72;
    const int lane = tid & 63, wv = tid >> 6;
    const int lo = lane & 15, quad = lane >> 4;
    const int colg = tid >> 5;                        // 0..15 staging col group
    const int slice = tid & 31;                       // 8-ch (16B) slice
    const bool real4 = (colg < 8);                    // unit-4 col < 72 (wave-uniform)

    int u_pq[5];
    const float* u_off[5];
    const unsigned short* u_vT[5];
#pragma unroll
    for (int u = 0; u < 5; u++) {
        int cl = colg + u * 16;
        int cg = min(c0 + cl, 18431);
        int pq = cg >> 3, n = cg & 7;
        u_pq[u] = pq;
        u_off[u] = off + (size_t)(n >> 2) * 18 * HWP + pq;
        u_vT[u]  = vT + (size_t)n * HWP * 256 + slice * 8;
    }

    floatx4 acc[2][5];
#pragma unroll
    for (int mt = 0; mt < 2; mt++)
#pragma unroll
        for (int nt = 0; nt < 5; nt++) acc[mt][nt] = (floatx4)0.f;

    short8 P[5][4];
    float  cwt[5][4];
    float  ndy[5], ndx[5];

    auto prefetch_off = [&](int tap) {
#pragma unroll
        for (int u = 0; u < 5; u++) {
            if (u < 4 || real4) {
                ndy[u] = u_off[u][(2 * tap) * HWP];
                ndx[u] = u_off[u][(2 * tap + 1) * HWP];
            }
        }
    };

    auto prefetch_body = [&](int tap) {
        const float kdy = (float)(tap / 3 - 1), kdx = (float)(tap % 3 - 1);
#pragma unroll
        for (int u = 0; u < 5; u++) {
            if (u < 4 || real4) {
                int pq = u_pq[u];
                int h = pq / WW, w = pq - (pq / WW) * WW;
                float py = ndy[u] + (float)h + kdy;
                float px = ndx[u] + (float)w + kdx;
                float y0f = floorf(py), x0f = floorf(px);
                int y0 = (int)y0f, x0 = (int)x0f;
                float fy = py - y0f, fx = px - x0f;
                bool y0ok = (y0 >= 0) & (y0 < HH), y1ok = (y0 >= -1) & (y0 < HH - 1);
                bool x0ok = (x0 >= 0) & (x0 < WW), x1ok = (x0 >= -1) & (x0 < WW - 1);
                int y0c = min(max(y0, 0), HH - 1), y1c = min(max(y0 + 1, 0), HH - 1);
                int x0c = min(max(x0, 0), WW - 1), x1c = min(max(x0 + 1, 0), WW - 1);
                const unsigned short* r0 = u_vT[u] + (size_t)(y0c * WW + x0c) * 256;
                const unsigned short* r1 = u_vT[u] + (size_t)(y0c * WW + x1c) * 256;
                const unsigned short* r2 = u_vT[u] + (size_t)(y1c * WW + x0c) * 256;
                const unsigned short* r3 = u_vT[u] + (size_t)(y1c * WW + x1c) * 256;
                cwt[u][0] = (y0ok && x0ok) ? (1.f - fy) * (1.f - fx) : 0.f;
                cwt[u][1] = (y0ok && x1ok) ? (1.f - fy) * fx         : 0.f;
                cwt[u][2] = (y1ok && x0ok) ? fy * (1.f - fx)         : 0.f;
                cwt[u][3] = (y1ok && x1ok) ? fy * fx                 : 0.f;
                P[u][0] = *(const short8*)(r0);
                P[u][1] = *(const short8*)(r1);
                P[u][2] = *(const short8*)(r2);
                P[u][3] = *(const short8*)(r3);
            }
        }
    };

    prefetch_off(0);
    prefetch_body(0);
    int buf = 0;

    for (int tap = 0; tap < 9; tap++) {
        if (tap < 8) prefetch_off(tap + 1);
        unsigned short* sb = &Sl[buf][0];
#pragma unroll
        for (int u = 0; u < 5; u++) {
            if (u < 4 || real4) {
                float w0 = cwt[u][0], w1 = cwt[u][1], w2 = cwt[u][2], w3 = cwt[u][3];
                short8 ov;
#pragma unroll
                for (int j = 0; j < 8; j++) {
                    float s = w0 * bf2f(P[u][0][j]) + w1 * bf2f(P[u][1][j])
                            + w2 * bf2f(P[u][2][j]) + w3 * bf2f(P[u][3][j]);
                    ov[j] = (short)f2bf(s);
                }
                int cl = colg + u * 16;
                int slot = slice ^ (cl & 7);
                *(short8*)(sb + cl * 256 + slot * 8) = ov;
            }
        }
        __syncthreads();

        if (tap < 8) prefetch_body(tap + 1);

        const unsigned short* afr = wdr + (((size_t)tap * 8 * 16 + wv * 2) * 64 + lane) * 8;
#pragma unroll
        for (int ks = 0; ks < 8; ks++) {
            const unsigned short* ak = afr + (size_t)ks * 16 * 512;
            short8 a0 = *(const short8*)(ak);
            short8 a1 = *(const short8*)(ak + 512);
#pragma unroll
            for (int nt = 0; nt < 5; nt++) {
                int cl = nt * 16 + lo;
                int clc = min(cl, 71);                // rows 72-79 alias 71; cols discarded
                int slot = (ks * 4 + quad) ^ (clc & 7);
                short8 bf = *(const short8*)(sb + clc * 256 + slot * 8);
                acc[0][nt] = __builtin_amdgcn_mfma_f32_16x16x32_bf16(a0, bf, acc[0][nt], 0, 0, 0);
                acc[1][nt] = __builtin_amdgcn_mfma_f32_16x16x32_bf16(a1, bf, acc[1][nt], 0, 0, 0);
            }
        }
        __syncthreads();
        buf ^= 1;
    }

    // epilogue: out[col][o] = acc + db[o] + qT[pq][b][o]   (col = pq*8+n)
#pragma unroll
    for (int mt = 0; mt < 2; mt++) {
        int o = wv * 32 + mt * 16 + quad * 4;
        float d0 = db[o], d1 = db[o + 1], d2 = db[o + 2], d3 = db[o + 3];
#pragma unroll
        for (int nt = 0; nt < 5; nt++) {
            int cl = nt * 16 + lo;
            if (cl < 72) {
                int cg = c0 + cl;
                int pq = cg >> 3, b = (cg & 7) >> 2;
                floatx4 qv = *(const floatx4*)(qT + ((size_t)pq * 2 + b) * 256 + o);
                floatx4 r = acc[mt][nt];
                r[0] += d0 + qv[0];
                r[1] += d1 + qv[1];
                r[2] += d2 + qv[2];
                r[3] += d3 + qv[3];
                *(floatx4*)(out + (size_t)cg * CC + o) = r;
            }
        }
    }
}

extern "C" void kernel_launch(void* const* d_in, const int* in_sizes, int n_in,
                              void* d_out, int out_size, void* d_ws, size_t ws_size,
                              hipStream_t stream) {
    const float* q  = (const float*)d_in[0];
    const float* k  = (const float*)d_in[1];
    const float* v  = (const float*)d_in[2];
    const float* w1 = (const float*)d_in[3];
    const float* b1 = (const float*)d_in[4];
    const float* w2 = (const float*)d_in[5];
    const float* b2 = (const float*)d_in[6];
    const float* dw = (const float*)d_in[7];
    const float* db = (const float*)d_in[8];
    float* out = (float*)d_out;

    // ws layout (~40 MB): off | qT (dead feat3 region) | (off9 dead) || qkT | vT | featb | w1r | wdr | w2r
    float* off   = (float*)d_ws;                          //    82,944 f
    float* qT    = off + 82944;                           // 1,179,648 f used
    float* off9  = qT + 3538944;                          // dead (kept for layout)
    unsigned short* qkT   = (unsigned short*)(off9 + 1327104);
    unsigned short* vT    = qkT + 2360320;                // 2*2305*512
    unsigned short* featb = vT + 4718592;                 // 2*2305*256
    unsigned short* w1r   = featb + 1180160;              // frag order
    unsigned short* wdr   = w1r + 1179648;
    unsigned short* w2r   = wdr + 589824;

    hipLaunchKernelGGL(k_trprep,dim3(8929),      dim3(256), 0, stream,
                       q, k, v, w1, dw, w2, qkT, qT, vT, w1r, wdr, w2r, featb);
    hipLaunchKernelGGL(k_conv1, dim3(72, 2, 2),  dim3(512), 0, stream, qkT, w1r, b1, featb);
    hipLaunchKernelGGL(k_conv2, dim3(36, 2),     dim3(512), 0, stream, featb, w2r, b2, off);
    hipLaunchKernelGGL(k_deform,dim3(256),       dim3(512), 0, stream, vT, off, wdr, db, qT, out);
}

// Round 16
// 198.719 us; speedup vs baseline: 1.2651x; 1.0055x over previous
//
#include <hip/hip_runtime.h>

// Problem constants: B=2, obj=4, C=256, H=W=48, N=8, HW=2304
#define HH 48
#define WW 48
#define HWP 2304
#define CC 256
#define NB 8
#define QKROW 2305   // 2304 rows + 1 zero pad row (index 2304) for OOB taps

typedef __attribute__((ext_vector_type(8))) short short8;   // 8 x bf16 = 4 VGPR
typedef __attribute__((ext_vector_type(4))) short bf16x4;   // 4 x bf16 = 8B
typedef __attribute__((ext_vector_type(4))) float floatx4;  // MFMA C/D frag

static __device__ __forceinline__ unsigned short f2bf(float f) {
    union { float f; unsigned u; } v; v.f = f;
    unsigned r = v.u + 0x7fffu + ((v.u >> 16) & 1u);        // RNE
    return (unsigned short)(r >> 16);
}
static __device__ __forceinline__ float bf2f(short v) {
    union { unsigned u; float f; } x; x.u = ((unsigned)(unsigned short)v) << 16;
    return x.f;
}

// ---- merged: bid<7201 -> weight preshuffle (+pad zero); else transposes ----
// tr loads now float4 (was 16 scalar fp32/thread -> 4 vec4): Common-mistake #2.
__global__ __launch_bounds__(256) void k_trprep(const float* __restrict__ q,
        const float* __restrict__ kk, const float* __restrict__ v,
        const float* __restrict__ w1, const float* __restrict__ dw,
        const float* __restrict__ w2, unsigned short* __restrict__ qkT,
        float* __restrict__ qT, unsigned short* __restrict__ vT,
        unsigned short* __restrict__ w1r, unsigned short* __restrict__ wdr,
        unsigned short* __restrict__ w2r, unsigned short* __restrict__ featb) {
    __shared__ float T[64][65];
    const int bid = blockIdx.x;
    if (bid < 7201) {
        if (bid == 7200) {
            int t = threadIdx.x;
#pragma unroll
            for (int b = 0; b < 2; b++) {
                qkT[((size_t)b * QKROW + HWP) * 512 + t] = 0;
                qkT[((size_t)b * QKROW + HWP) * 512 + 256 + t] = 0;
                featb[((size_t)b * QKROW + HWP) * 256 + t] = 0;
            }
            return;
        }
        int idx = bid * 256 + threadIdx.x;
        if (idx < 1179648) {
            int j = idx & 7, l = (idx >> 3) & 63, mtg = (idx >> 9) & 15;
            int kkk = (idx >> 13) & 15, tap = idx >> 17;
            int o = mtg * 16 + (l & 15);
            int c2 = kkk * 32 + (l >> 4) * 8 + j;
            w1r[idx] = f2bf(w1[((size_t)o * 512 + c2) * 9 + tap]);
        } else if (idx < 1179648 + 589824) {
            int i2 = idx - 1179648;
            int j = i2 & 7, l = (i2 >> 3) & 63, mtg = (i2 >> 9) & 15;
            int kkk = (i2 >> 13) & 7, tap = i2 >> 16;
            int o = mtg * 16 + (l & 15);
            int c = kkk * 32 + (l >> 4) * 8 + j;
            wdr[i2] = f2bf(dw[((size_t)o * 256 + c) * 9 + tap]);
        } else {
            int i2 = idx - 1179648 - 589824;
            int j = i2 & 7, l = (i2 >> 3) & 63, mt = (i2 >> 9) & 1;
            int kkk = (i2 >> 10) & 7, tap = i2 >> 13;
            int o = mt * 16 + (l & 15);
            int c = kkk * 32 + (l >> 4) * 8 + j;
            w2r[i2] = (o < 18) ? f2bf(w2[((size_t)o * 256 + c) * 9 + tap]) : 0;
        }
        return;
    }
    const int idx2 = bid - 7201;           // 0..1727
    const int pg = idx2 % 36;
    const int rest = idx2 / 36;
    const int cg = rest & 3, z = rest >> 2;   // cg 0..3, z 0..11
    const int tx = threadIdx.x & 63, ty = threadIdx.x >> 6;
    const int t4 = threadIdx.x & 15, r4 = threadIdx.x >> 4;   // float4 load decomp
    const float* s;
    if (z < 4) {
        const int b = z >> 1, src = z & 1;
        s = (src ? kk : q) + (size_t)b * CC * HWP;
#pragma unroll
        for (int i = 0; i < 4; i++) {
            int cl = i * 16 + r4;
            float4 val = *(const float4*)(s + (size_t)(cg * 64 + cl) * HWP + pg * 64 + t4 * 4);
            T[cl][t4 * 4 + 0] = val.x;
            T[cl][t4 * 4 + 1] = val.y;
            T[cl][t4 * 4 + 2] = val.z;
            T[cl][t4 * 4 + 3] = val.w;
        }
        __syncthreads();
#pragma unroll
        for (int i = 0; i < 16; i++) {
            int pxl = ty * 16 + i;
            float val = T[tx][pxl];
            qkT[((size_t)b * QKROW + pg * 64 + pxl) * 512 + src * 256 + cg * 64 + tx]
                = f2bf(val);
            if (src == 0)
                qT[((size_t)(pg * 64 + pxl) * 2 + b) * 256 + cg * 64 + tx] = val;
        }
    } else {
        const int n = z - 4;
        s = v + (size_t)n * CC * HWP;
#pragma unroll
        for (int i = 0; i < 4; i++) {
            int cl = i * 16 + r4;
            float4 val = *(const float4*)(s + (size_t)(cg * 64 + cl) * HWP + pg * 64 + t4 * 4);
            T[cl][t4 * 4 + 0] = val.x;
            T[cl][t4 * 4 + 1] = val.y;
            T[cl][t4 * 4 + 2] = val.z;
            T[cl][t4 * 4 + 3] = val.w;
        }
        __syncthreads();
#pragma unroll
        for (int i = 0; i < 16; i++) {
            int pxl = ty * 16 + i;
            vT[((size_t)n * HWP + pg * 64 + pxl) * 256 + cg * 64 + tx] = f2bf(T[tx][pxl]);
        }
    }
}

// ---- conv1 v3: k_deform-structure port (verified round 9, ~30us) -----------
__global__ __launch_bounds__(512, 4) void k_conv1(const unsigned short* __restrict__ qkT,
        const unsigned short* __restrict__ w1r, const float* __restrict__ b1,
        unsigned short* __restrict__ featb) {
    __shared__ __align__(16) unsigned short Bl[2][32 * 64 * 8];   // 2 x 32 KB

    const int tid = threadIdx.x;          // 0..511
    const int pt = blockIdx.x;            // 72 px-tiles of 32
    const int b  = blockIdx.y;
    const int oh = blockIdx.z;            // out half (128 outs)
    const int px0 = pt * 32;
    const int lane = tid & 63, wv = tid >> 6;   // 8 waves
    const int lo = lane & 15, quad = lane >> 4;
    const int mtg = oh * 8 + wv;          // this wave's 16-out group

    floatx4 acc[2];
    acc[0] = (floatx4)0.f; acc[1] = (floatx4)0.f;

    short8 R[4];                          // prefetched staging rows (next tap)
    auto stage_load = [&](int tap) {
        const int dy = tap / 3 - 1, dx = tap % 3 - 1;
#pragma unroll
        for (int k = 0; k < 4; k++) {
            int seg = tid + k * 512;      // 0..2047
            int cl  = seg >> 6;           // LDS row = output px0+cl
            int sl  = seg & 63;           // 16B slot within 512-ch row
            int px  = px0 + cl;
            int h = px / WW, w = px - (px / WW) * WW;
            bool val = (h + dy >= 0) && (h + dy < HH)
                       && (w + dx >= 0) && (w + dx < WW);
            int row = val ? (px + dy * WW + dx) : HWP;   // pad row = zeros
            R[k] = *(const short8*)(qkT + ((size_t)b * QKROW + row) * 512 + sl * 8);
        }
    };

    stage_load(0);
    int buf = 0;

    for (int tap = 0; tap < 9; tap++) {
        unsigned short* sb = &Bl[buf][0];
#pragma unroll
        for (int k = 0; k < 4; k++) {
            int seg = tid + k * 512;
            int cl = seg >> 6, sl = seg & 63;
            int slw = sl ^ (cl & 7);      // XOR bank swizzle
            *(short8*)(sb + ((size_t)cl * 64 + slw) * 8) = R[k];
        }
        __syncthreads();                  // dbuf: single barrier per tap is safe

        if (tap < 8) stage_load(tap + 1); // loads land during GEMM below

        const unsigned short* afr = w1r + (((size_t)tap * 16 * 16 + mtg) * 64 + lane) * 8;
#pragma unroll 4
        for (int ks = 0; ks < 16; ks++) {
            short8 a = *(const short8*)(afr + (size_t)ks * 16 * 512);
#pragma unroll
            for (int nt = 0; nt < 2; nt++) {
                int cl = nt * 16 + lo;
                int slot = (ks * 4 + quad) ^ (cl & 7);
                short8 bf = *(const short8*)(sb + ((size_t)cl * 64 + slot) * 8);
                acc[nt] = __builtin_amdgcn_mfma_f32_16x16x32_bf16(a, bf, acc[nt], 0, 0, 0);
            }
        }
        buf ^= 1;
    }

    // epilogue: featb[b][px][o] = bf16(acc + b1[o]);  o = mtg*16 + quad*4 + i
    const int o = mtg * 16 + quad * 4;
    const float b0 = b1[o], bb1 = b1[o + 1], bb2 = b1[o + 2], bb3 = b1[o + 3];
#pragma unroll
    for (int nt = 0; nt < 2; nt++) {
        int px = px0 + nt * 16 + lo;
        bf16x4 pk;
        pk[0] = (short)f2bf(acc[nt][0] + b0);
        pk[1] = (short)f2bf(acc[nt][1] + bb1);
        pk[2] = (short)f2bf(acc[nt][2] + bb2);
        pk[3] = (short)f2bf(acc[nt][3] + bb3);
        *(bf16x4*)(featb + ((size_t)b * QKROW + px) * 256 + o) = pk;
    }
}

// ---- conv2 v3: 288 blocks x 128 thr (was 72x512 -> only 72 CUs busy) -------
// 144 px-tiles of 16 x 2 b; 2 waves = 2 mtg. Same dbuf/prefetch skeleton and
// frag indices (cl=lo is the pxb=0 case of the verified mapping). Spreads the
// same work over all 256 CUs: ~16us -> ~5us.
__global__ __launch_bounds__(128) void k_conv2(const unsigned short* __restrict__ featb,
        const unsigned short* __restrict__ w2r, const float* __restrict__ b2,
        float* __restrict__ off) {
    __shared__ __align__(16) unsigned short Bl[2][16 * 32 * 8];   // 2 x 8 KB

    const int tid = threadIdx.x;          // 0..127
    const int pt = blockIdx.x;            // 144 px-tiles of 16
    const int b  = blockIdx.y;
    const int px0 = pt * 16;
    const int lane = tid & 63, wv = tid >> 6;   // 2 waves
    const int lo = lane & 15, quad = lane >> 4;
    const int mtg = wv;                   // 16-out group (only o<18 stored)

    floatx4 acc = (floatx4)0.f;

    short8 R[4];
    auto stage_load = [&](int tap) {
        const int dy = tap / 3 - 1, dx = tap % 3 - 1;
#pragma unroll
        for (int k = 0; k < 4; k++) {
            int seg = tid + k * 128;      // 0..511 = cl*32 + sl
            int cl  = seg >> 5;           // 16 rows
            int sl  = seg & 31;           // 16B slot within 256-ch row
            int px  = px0 + cl;
            int h = px / WW, w = px - (px / WW) * WW;
            bool val = (h + dy >= 0) && (h + dy < HH)
                       && (w + dx >= 0) && (w + dx < WW);
            int row = val ? (px + dy * WW + dx) : HWP;   // pad row = zeros
            R[k] = *(const short8*)(featb + ((size_t)b * QKROW + row) * 256 + sl * 8);
        }
    };

    stage_load(0);
    int buf = 0;

    for (int tap = 0; tap < 9; tap++) {
        unsigned short* sb = &Bl[buf][0];
#pragma unroll
        for (int k = 0; k < 4; k++) {
            int seg = tid + k * 128;
            int cl = seg >> 5, sl = seg & 31;
            int slw = sl ^ (cl & 7);      // XOR bank swizzle
            *(short8*)(sb + ((size_t)cl * 32 + slw) * 8) = R[k];
        }
        __syncthreads();                  // dbuf: single barrier per tap (conv1-v3 proof)

        if (tap < 8) stage_load(tap + 1);

#pragma unroll
        for (int ks = 0; ks < 8; ks++) {
            short8 a = *(const short8*)(w2r + ((((size_t)tap * 8 + ks) * 2 + mtg) * 64 + lane) * 8);
            int cl = lo;
            int slot = (ks * 4 + quad) ^ (cl & 7);
            short8 bf = *(const short8*)(sb + ((size_t)cl * 32 + slot) * 8);
            acc = __builtin_amdgcn_mfma_f32_16x16x32_bf16(a, bf, acc, 0, 0, 0);
        }
        buf ^= 1;
    }

    // epilogue: off[b][oc][px] = acc + b2[oc], oc < 18 only
    const int o = mtg * 16 + quad * 4;
    const int px = px0 + lo;
#pragma unroll
    for (int i = 0; i < 4; i++) {
        int oc = o + i;
        if (oc < 18)
            off[((size_t)b * 18 + oc) * HWP + px] = acc[i] + b2[oc];
    }
}

// ---- deform: col-space tiling, 72-row LDS, phantom skip (round-15, 63.9us) -
// Grid=256 = 1 block/CU caps occupancy at ~20% regardless of LDS; smaller
// column tiles would multiply weight addrs (net loss per addr model). Near
// its structural floor (~205K lane-addrs/CU -> ~58us model).
__global__ __launch_bounds__(512, 2) void k_deform(const unsigned short* __restrict__ vT,
        const float* __restrict__ off, const unsigned short* __restrict__ wdr,
        const float* __restrict__ db, const float* __restrict__ qT,
        float* __restrict__ out) {
    __shared__ __align__(16) unsigned short Sl[2][72 * 256];   // 2 x 36 KB

    const int tid = threadIdx.x;
    const int bid = blockIdx.x;                       // 256
    const int c0 = (((bid & 7) << 5) + (bid >> 3)) * 72;
    const int lane = tid & 63, wv = tid >> 6;
    const int lo = lane & 15, quad = lane >> 4;
    const int colg = tid >> 5;                        // 0..15 staging col group
    const int slice = tid & 31;                       // 8-ch (16B) slice
    const bool real4 = (colg < 8);                    // unit-4 col < 72 (wave-uniform)

    int u_pq[5];
    const float* u_off[5];
    const unsigned short* u_vT[5];
#pragma unroll
    for (int u = 0; u < 5; u++) {
        int cl = colg + u * 16;
        int cg = min(c0 + cl, 18431);
        int pq = cg >> 3, n = cg & 7;
        u_pq[u] = pq;
        u_off[u] = off + (size_t)(n >> 2) * 18 * HWP + pq;
        u_vT[u]  = vT + (size_t)n * HWP * 256 + slice * 8;
    }

    floatx4 acc[2][5];
#pragma unroll
    for (int mt = 0; mt < 2; mt++)
#pragma unroll
        for (int nt = 0; nt < 5; nt++) acc[mt][nt] = (floatx4)0.f;

    short8 P[5][4];
    float  cwt[5][4];
    float  ndy[5], ndx[5];

    auto prefetch_off = [&](int tap) {
#pragma unroll
        for (int u = 0; u < 5; u++) {
            if (u < 4 || real4) {
                ndy[u] = u_off[u][(2 * tap) * HWP];
                ndx[u] = u_off[u][(2 * tap + 1) * HWP];
            }
        }
    };

    auto prefetch_body = [&](int tap) {
        const float kdy = (float)(tap / 3 - 1), kdx = (float)(tap % 3 - 1);
#pragma unroll
        for (int u = 0; u < 5; u++) {
            if (u < 4 || real4) {
                int pq = u_pq[u];
                int h = pq / WW, w = pq - (pq / WW) * WW;
                float py = ndy[u] + (float)h + kdy;
                float px = ndx[u] + (float)w + kdx;
                float y0f = floorf(py), x0f = floorf(px);
                int y0 = (int)y0f, x0 = (int)x0f;
                float fy = py - y0f, fx = px - x0f;
                bool y0ok = (y0 >= 0) & (y0 < HH), y1ok = (y0 >= -1) & (y0 < HH - 1);
                bool x0ok = (x0 >= 0) & (x0 < WW), x1ok = (x0 >= -1) & (x0 < WW - 1);
                int y0c = min(max(y0, 0), HH - 1), y1c = min(max(y0 + 1, 0), HH - 1);
                int x0c = min(max(x0, 0), WW - 1), x1c = min(max(x0 + 1, 0), WW - 1);
                const unsigned short* r0 = u_vT[u] + (size_t)(y0c * WW + x0c) * 256;
                const unsigned short* r1 = u_vT[u] + (size_t)(y0c * WW + x1c) * 256;
                const unsigned short* r2 = u_vT[u] + (size_t)(y1c * WW + x0c) * 256;
                const unsigned short* r3 = u_vT[u] + (size_t)(y1c * WW + x1c) * 256;
                cwt[u][0] = (y0ok && x0ok) ? (1.f - fy) * (1.f - fx) : 0.f;
                cwt[u][1] = (y0ok && x1ok) ? (1.f - fy) * fx         : 0.f;
                cwt[u][2] = (y1ok && x0ok) ? fy * (1.f - fx)         : 0.f;
                cwt[u][3] = (y1ok && x1ok) ? fy * fx                 : 0.f;
                P[u][0] = *(const short8*)(r0);
                P[u][1] = *(const short8*)(r1);
                P[u][2] = *(const short8*)(r2);
                P[u][3] = *(const short8*)(r3);
            }
        }
    };

    prefetch_off(0);
    prefetch_body(0);
    int buf = 0;

    for (int tap = 0; tap < 9; tap++) {
        if (tap < 8) prefetch_off(tap + 1);
        unsigned short* sb = &Sl[buf][0];
#pragma unroll
        for (int u = 0; u < 5; u++) {
            if (u < 4 || real4) {
                float w0 = cwt[u][0], w1 = cwt[u][1], w2 = cwt[u][2], w3 = cwt[u][3];
                short8 ov;
#pragma unroll
                for (int j = 0; j < 8; j++) {
                    float s = w0 * bf2f(P[u][0][j]) + w1 * bf2f(P[u][1][j])
                            + w2 * bf2f(P[u][2][j]) + w3 * bf2f(P[u][3][j]);
                    ov[j] = (short)f2bf(s);
                }
                int cl = colg + u * 16;
                int slot = slice ^ (cl & 7);
                *(short8*)(sb + cl * 256 + slot * 8) = ov;
            }
        }
        __syncthreads();

        if (tap < 8) prefetch_body(tap + 1);

        const unsigned short* afr = wdr + (((size_t)tap * 8 * 16 + wv * 2) * 64 + lane) * 8;
#pragma unroll
        for (int ks = 0; ks < 8; ks++) {
            const unsigned short* ak = afr + (size_t)ks * 16 * 512;
            short8 a0 = *(const short8*)(ak);
            short8 a1 = *(const short8*)(ak + 512);
#pragma unroll
            for (int nt = 0; nt < 5; nt++) {
                int cl = nt * 16 + lo;
                int clc = min(cl, 71);                // rows 72-79 alias 71; cols discarded
                int slot = (ks * 4 + quad) ^ (clc & 7);
                short8 bf = *(const short8*)(sb + clc * 256 + slot * 8);
                acc[0][nt] = __builtin_amdgcn_mfma_f32_16x16x32_bf16(a0, bf, acc[0][nt], 0, 0, 0);
                acc[1][nt] = __builtin_amdgcn_mfma_f32_16x16x32_bf16(a1, bf, acc[1][nt], 0, 0, 0);
            }
        }
        __syncthreads();
        buf ^= 1;
    }

    // epilogue: out[col][o] = acc + db[o] + qT[pq][b][o]   (col = pq*8+n)
#pragma unroll
    for (int mt = 0; mt < 2; mt++) {
        int o = wv * 32 + mt * 16 + quad * 4;
        float d0 = db[o], d1 = db[o + 1], d2 = db[o + 2], d3 = db[o + 3];
#pragma unroll
        for (int nt = 0; nt < 5; nt++) {
            int cl = nt * 16 + lo;
            if (cl < 72) {
                int cg = c0 + cl;
                int pq = cg >> 3, b = (cg & 7) >> 2;
                floatx4 qv = *(const floatx4*)(qT + ((size_t)pq * 2 + b) * 256 + o);
                floatx4 r = acc[mt][nt];
                r[0] += d0 + qv[0];
                r[1] += d1 + qv[1];
                r[2] += d2 + qv[2];
                r[3] += d3 + qv[3];
                *(floatx4*)(out + (size_t)cg * CC + o) = r;
            }
        }
    }
}

extern "C" void kernel_launch(void* const* d_in, const int* in_sizes, int n_in,
                              void* d_out, int out_size, void* d_ws, size_t ws_size,
                              hipStream_t stream) {
    const float* q  = (const float*)d_in[0];
    const float* k  = (const float*)d_in[1];
    const float* v  = (const float*)d_in[2];
    const float* w1 = (const float*)d_in[3];
    const float* b1 = (const float*)d_in[4];
    const float* w2 = (const float*)d_in[5];
    const float* b2 = (const float*)d_in[6];
    const float* dw = (const float*)d_in[7];
    const float* db = (const float*)d_in[8];
    float* out = (float*)d_out;

    // ws layout (~40 MB): off | qT (dead feat3 region) | (off9 dead) || qkT | vT | featb | w1r | wdr | w2r
    float* off   = (float*)d_ws;                          //    82,944 f
    float* qT    = off + 82944;                           // 1,179,648 f used
    float* off9  = qT + 3538944;                          // dead (kept for layout)
    unsigned short* qkT   = (unsigned short*)(off9 + 1327104);
    unsigned short* vT    = qkT + 2360320;                // 2*2305*512
    unsigned short* featb = vT + 4718592;                 // 2*2305*256
    unsigned short* w1r   = featb + 1180160;              // frag order
    unsigned short* wdr   = w1r + 1179648;
    unsigned short* w2r   = wdr + 589824;

    hipLaunchKernelGGL(k_trprep,dim3(8929),      dim3(256), 0, stream,
                       q, k, v, w1, dw, w2, qkT, qT, vT, w1r, wdr, w2r, featb);
    hipLaunchKernelGGL(k_conv1, dim3(72, 2, 2),  dim3(512), 0, stream, qkT, w1r, b1, featb);
    hipLaunchKernelGGL(k_conv2, dim3(144, 2),    dim3(128), 0, stream, featb, w2r, b2, off);
    hipLaunchKernelGGL(k_deform,dim3(256),       dim3(512), 0, stream, vT, off, wdr, db, qT, out);
}